// Round 8
// baseline (777.945 us; speedup 1.0000x reference)
//
#include <hip/hip_runtime.h>
#include <hip/hip_bf16.h>
#include <stdint.h>

// STU forward: y = scan(m_y, (x_tilde @ m_phi) + AR(m_u, u))
// R5: 256x128 MFMA tiles for the two big GEMMs.
// R6: XCD-chunked blockIdx swizzle (T1).
// R7: k_gemm_delta s-major enumeration (FETCH 188->84 MB, verified).
// R8: T3 prefetch pipeline on k_gemm_zt / k_gemm_delta: double-buffered LDS
// (96 KB, 1 block/CU), stage slab t+1 before MFMA of slab t, single
// vmcnt(0)+s_barrier per slab (raw barrier; no full __syncthreads drain).

typedef unsigned short u16;
typedef unsigned int   u32;
typedef __bf16  bf16x8 __attribute__((ext_vector_type(8)));
typedef float   f32x4  __attribute__((ext_vector_type(4)));
typedef u32     u32x4  __attribute__((ext_vector_type(4)));

#define MFMA(a,b,c) __builtin_amdgcn_mfma_f32_16x16x32_bf16(a,b,c,0,0,0)
#define RJ 1179648   // elems per R_j (768*1536)

__device__ __forceinline__ u16 f2b(float f) {           // fp32 -> bf16 bits, RNE
  union { float f; u32 u; } v; v.f = f;
  return (u16)((v.u + 0x7fffu + ((v.u >> 16) & 1u)) >> 16);
}

__device__ __forceinline__ void gld16(const u16* g, u16* l) {
  __builtin_amdgcn_global_load_lds(
      (const __attribute__((address_space(1))) u32*)g,
      (__attribute__((address_space(3))) u32*)l, 16, 0, 0);
}

// pipeline sync helpers (raw barrier; vmcnt-only drain)
__device__ __forceinline__ void pipe_sync() {
  asm volatile("s_waitcnt vmcnt(0)" ::: "memory");
  __builtin_amdgcn_s_barrier();
  __builtin_amdgcn_sched_barrier(0);
}

// ---------------- workspace layout (bytes) ----------------
#define WS_UB     0            // [2050][768] bf16
#define WS_MPHIT  3148800      // [18432][768] bf16
#define WS_B2T    31460352     // [3][768][768] bf16
#define WS_TT     34999296     // [17][24][128][128] bf16 (slot 0 = delta-tile for dlt=-1, all zero)
#define WS_ZT     48368640     // [24][768][2048] bf16 (dead after k_gemm_delta)
#define WS_DELTA  123866112    // [2048][768] f32  (end 130157568)
// overlays inside zt region (phase 2, after k_gemm_delta):
#define OV_RBIG   (WS_ZT + 0)          // [9][768][1536] bf16
#define OV_CT0    (WS_ZT + 21233664)   // [1536][1536] bf16
#define OV_CT1    (WS_ZT + 25952256)
#define OV_CT2    (WS_ZT + 30670848)
#define OV_HBUF   (WS_ZT + 35389440)   // [2048][768] f32
#define OV_SBUF   (WS_ZT + 41680896)   // [2][256][1536] bf16

// ---------------------------------------------------------------------------
// k_prep: zero delta | repack u | repack mphi | repack mu | make_T  (one launch)
__global__ void k_prep(const float* __restrict__ u, const float* __restrict__ mphi,
                       const float* __restrict__ ev, const float* __restrict__ mu,
                       const float* __restrict__ evec,
                       float* __restrict__ delta, u16* __restrict__ ub,
                       u16* __restrict__ mphiT, u16* __restrict__ b2t,
                       u16* __restrict__ tt) {
  __shared__ float tile[32][33];
  int b = blockIdx.x, tid = threadIdx.x;
  if (b < 6144) {                       // zero delta
    delta[b * 256 + tid] = 0.f;
  } else if (b < 12294) {               // repack u (+2 guard rows)
    int i = (b - 6144) * 256 + tid;
    ub[i] = (i < 2 * 768) ? (u16)0 : f2b(u[i - 2 * 768]);
  } else if (b < 26118) {               // repack mphi (transpose per k, scale)
    int bid = b - 12294;
    int k = bid / 576, rem = bid % 576;
    int ti = rem / 24, tj = rem % 24;
    int c = tid & 31, r0 = tid >> 5;
    float s = powf(ev[k], 0.25f);
    #pragma unroll
    for (int rr = 0; rr < 4; ++rr) {
      int r = r0 + (rr << 3);
      tile[r][c] = mphi[(k * 768 + ti * 32 + r) * 768 + tj * 32 + c];
    }
    __syncthreads();
    #pragma unroll
    for (int rr = 0; rr < 4; ++rr) {
      int r = r0 + (rr << 3);
      mphiT[(k * 768 + tj * 32 + r) * 768 + ti * 32 + c] = f2b(tile[c][r] * s);
    }
  } else if (b < 33030) {               // repack mu
    int i = (b - 26118) * 256 + tid;
    int kk = i / (768 * 768);
    int rem = i % (768 * 768);
    int o = rem / 768, ii = rem % 768;
    b2t[i] = f2b(mu[(o * 768 + ii) * 3 + kk]);
  } else {                              // make_T (17 slots; slot 0 auto-zero)
    int i = (b - 33030) * 256 + tid;
    int c = i & 127, r = (i >> 7) & 127;
    int kk = (i >> 14) % 24, sl = (i >> 14) / 24;
    int t = (sl - 1) * 128 + r - c - 2;
    tt[i] = (t >= 0 && t < 2048) ? f2b(evec[t * 24 + kk]) : (u16)0;
  }
}

// ---------------------------------------------------------------------------
// Stage 128 rows x 64 u16 (16 KB) via async global_load_lds, XOR-swizzled:
// LDS slot (row, cb) holds global (row, cb ^ (row&7)).
__device__ __forceinline__ void stage128(const u16* __restrict__ g, int ld,
                                         u16* __restrict__ lds) {
  int tid = threadIdx.x;
  int r0 = tid >> 3, cb = tid & 7, wave = tid >> 6;
  #pragma unroll
  for (int s = 0; s < 4; ++s) {
    int row = r0 + (s << 5);
    int cbx = (cb ^ (row & 7)) << 3;
    gld16(g + row * ld + cbx, lds + (s << 11) + (wave << 9));
  }
}

// 128x128 tile MFMA over one K=64 slab (swizzle-aware reads).
__device__ __forceinline__ void mfma_tile(const u16* As, const u16* Bs, int lane,
                                          int wm, int wn, f32x4 acc[4][4]) {
  int cn = lane & 15, q = lane >> 4;
  #pragma unroll
  for (int ks = 0; ks < 2; ++ks) {
    int blk = ks * 4 + q;
    bf16x8 af[4], bg[4];
    #pragma unroll
    for (int i = 0; i < 4; ++i) {
      int row = wm + i * 16 + cn;
      af[i] = *(const bf16x8*)&As[row * 64 + ((blk ^ (row & 7)) << 3)];
    }
    #pragma unroll
    for (int j = 0; j < 4; ++j) {
      int row = wn + j * 16 + cn;
      bg[j] = *(const bf16x8*)&Bs[row * 64 + ((blk ^ (row & 7)) << 3)];
    }
    #pragma unroll
    for (int i = 0; i < 4; ++i)
      #pragma unroll
      for (int j = 0; j < 4; ++j)
        acc[i][j] = MFMA(af[i], bg[j], acc[i][j]);
  }
}

// 256x128 tile: wave owns 64 M-rows (wm = wave*64), all 128 N-cols. 32 MFMA/slab.
__device__ __forceinline__ void mfma_tile256(const u16* As, const u16* Bs, int lane,
                                             int wm, f32x4 acc[4][8]) {
  int cn = lane & 15, q = lane >> 4;
  #pragma unroll
  for (int ks = 0; ks < 2; ++ks) {
    int blk = ks * 4 + q;
    bf16x8 af[4], bg[8];
    #pragma unroll
    for (int i = 0; i < 4; ++i) {
      int row = wm + i * 16 + cn;
      af[i] = *(const bf16x8*)&As[row * 64 + ((blk ^ (row & 7)) << 3)];
    }
    #pragma unroll
    for (int j = 0; j < 8; ++j) {
      int row = j * 16 + cn;
      bg[j] = *(const bf16x8*)&Bs[row * 64 + ((blk ^ (row & 7)) << 3)];
    }
    #pragma unroll
    for (int i = 0; i < 4; ++i)
      #pragma unroll
      for (int j = 0; j < 8; ++j)
        acc[i][j] = MFMA(af[i], bg[j], acc[i][j]);
  }
}

// K2: Zt[18432 x 2048] = mphiT @ ub^T.  256x128 tiles, grid 72x16.
// R8: prefetch pipeline, dbuf LDS (96 KB).
__global__ __launch_bounds__(256, 1) void k_gemm_zt(const u16* __restrict__ A,
                                                    const u16* __restrict__ B,
                                                    u16* __restrict__ C) {
  __shared__ __align__(16) u16 As[2 * 256 * 64];
  __shared__ __align__(16) u16 Bs[2 * 128 * 64];
  int bid = blockIdx.x;
  bid = (bid & 7) * 144 + (bid >> 3);   // XCD chunk swizzle (1152/8 = 144)
  int nt = bid & 15, mt = bid >> 4;
  int m0 = mt << 8, n0 = nt << 7;
  int tid = threadIdx.x, lane = tid & 63, wave = tid >> 6;
  int wm = wave << 6;
  f32x4 acc[4][8] = {};

  auto STAGE = [&](int kb, int half) {
    u16* Ad = As + half * (256 * 64);
    u16* Bd = Bs + half * (128 * 64);
    stage128(A + m0 * 768 + kb * 64, 768, Ad);
    stage128(A + (m0 + 128) * 768 + kb * 64, 768, Ad + 8192);
    stage128(B + n0 * 768 + kb * 64, 768, Bd);
  };

  STAGE(0, 0);
  pipe_sync();
  int cur = 0;
  for (int kb = 0; kb < 12; ++kb) {
    if (kb + 1 < 12) STAGE(kb + 1, cur ^ 1);
    mfma_tile256(As + cur * (256 * 64), Bs + cur * (128 * 64), lane, wm, acc);
    if (kb + 1 < 12) pipe_sync();
    cur ^= 1;
  }
  int q = lane >> 4, cn = lane & 15;
  #pragma unroll
  for (int i = 0; i < 4; ++i)
    #pragma unroll
    for (int j = 0; j < 8; ++j)
      #pragma unroll
      for (int r = 0; r < 4; ++r) {
        int m = m0 + wm + i * 16 + q * 4 + r;
        int n = n0 + j * 16 + cn;
        C[m * 2048 + n] = f2b(acc[i][j][r]);
      }
}

// K3: delta = sum_k T_k @ Zt[k] + AR.  256x128 tiles; block = (db, a, s).
// Rows 0-127 of the A tile use dlt = 2a-s (slot dlt+1; slot 0 is all-zero),
// rows 128-255 use dlt = 2a+1-s.
// R7 enumeration: s-major (s -> db -> a); a in [s>>1, 8).
// R8: flattened slab index (48 main + 12*ntaps AR) + prefetch pipeline.
__global__ __launch_bounds__(256, 1) void k_gemm_delta(const u16* __restrict__ tt,
                                                       const u16* __restrict__ zt,
                                                       const u16* __restrict__ ub,
                                                       const u16* __restrict__ b2t,
                                                       float* __restrict__ delta) {
  __shared__ __align__(16) u16 As[2 * 256 * 64];
  __shared__ __align__(16) u16 Bs[2 * 128 * 64];
  int bid = blockIdx.x;
  bid = (bid & 7) * 54 + (bid >> 3);    // XCD chunk swizzle (432/8 = 54)
  int s = 0, rem = bid;
  for (;; ++s) { int c = 6 * (8 - (s >> 1)); if (rem < c) break; rem -= c; }
  int cnt = 8 - (s >> 1);
  int db = rem / cnt;
  int a  = (s >> 1) + rem % cnt;
  int n0 = db << 7;
  int tid = threadIdx.x, lane = tid & 63, wave = tid >> 6;
  int wm = wave << 6;
  f32x4 acc[4][8] = {};
  int d1 = 2 * a + 1 - s;                         // slot for lower half = d1+1
  const u16* A0 = tt + (size_t)d1 * 24 * 16384;         // slot d1 (= dlt0+1)
  const u16* A1 = tt + (size_t)(d1 + 1) * 24 * 16384;   // slot d1+1
  const u16* ztb = zt + n0 * 2048 + s * 128;
  // AR taps owned by this block: kku in {s .. s+ntaps-1}
  int ntaps = (s > 2) ? 0 : ((s == 2 * a + 1) ? (3 - s) : 1);
  int nslab = 48 + 12 * ntaps;

  auto STAGE = [&](int t, int half) {
    u16* Ad = As + half * (256 * 64);
    u16* Bd = Bs + half * (128 * 64);
    if (t < 48) {
      int kk = t >> 1, hf = t & 1;
      stage128(A0 + kk * 16384 + hf * 64, 128, Ad);
      stage128(A1 + kk * 16384 + hf * 64, 128, Ad + 8192);
      stage128(ztb + kk * (768 * 2048) + hf * 64, 2048, Bd);
    } else {
      int ti = t - 48;
      int kku = s + ti / 12;
      int ic = ti % 12;
      const u16* Au = ub + (2 + a * 256 - kku) * 768;
      stage128(Au + ic * 64, 768, Ad);
      stage128(Au + 128 * 768 + ic * 64, 768, Ad + 8192);
      stage128(b2t + kku * (768 * 768) + n0 * 768 + ic * 64, 768, Bd);
    }
  };

  STAGE(0, 0);
  pipe_sync();
  int cur = 0;
  for (int t = 0; t < nslab; ++t) {
    if (t + 1 < nslab) STAGE(t + 1, cur ^ 1);
    mfma_tile256(As + cur * (256 * 64), Bs + cur * (128 * 64), lane, wm, acc);
    if (t + 1 < nslab) pipe_sync();
    cur ^= 1;
  }
  int q = lane >> 4, cn = lane & 15;
  #pragma unroll
  for (int i = 0; i < 4; ++i)
    #pragma unroll
    for (int j = 0; j < 8; ++j)
      #pragma unroll
      for (int r = 0; r < 4; ++r) {
        int m = a * 256 + wm + i * 16 + q * 4 + r;
        int n = n0 + j * 16 + cn;
        unsafeAtomicAdd(&delta[m * 768 + n], acc[i][j][r]);
      }
}

// ---------------------------------------------------------------------------
// chain init: R_0=[I|0], R_1=[A1|A2], Ct0=[R_1;R_0]^T, Ct1 right half=R_1^T, zero H.
__global__ void k_chain_init(const float* __restrict__ my, u16* __restrict__ Rbig,
                             u16* __restrict__ Ct0, u16* __restrict__ Ct1,
                             float* __restrict__ Hbuf) {
  int b = blockIdx.x, tid = threadIdx.x;
  if (b < 4608) {                       // R_0, R_1
    int i = b * 256 + tid;
    int o = i / 1536, q = i % 1536;
    Rbig[i] = (q == o) ? (u16)0x3F80 : (u16)0;
    Rbig[RJ + i] = f2b(my[i]);
  } else if (b < 13824) {               // Ct0[n][p]
    int i = (b - 4608) * 256 + tid;
    int n = i / 1536, p = i % 1536;
    u16 v;
    if (p < 768) v = f2b(my[p * 1536 + n]);
    else         v = (p - 768 == n) ? (u16)0x3F80 : (u16)0;
    Ct0[i] = v;
  } else if (b < 18432) {               // Ct1[n][768+i] = R_1[i][n]
    int i = (b - 13824) * 256 + tid;
    int n = i / 768, ii = i % 768;
    Ct1[n * 1536 + 768 + ii] = f2b(my[ii * 1536 + n]);
  } else {                              // zero Hbuf
    int i = (b - 18432) * 256 + tid;
    Hbuf[i] = 0.f;
  }
}

// M x 1536 x 1536 GEMM (B = Ct, [n][k] layout). Dual epilogue: row-major out +
// optional transposed write into the next doubling's Ct.
// mode 0: none; 1: tcol=m (R_2^T -> left); 2: m<768 -> 768+m (R_3^T right),
// m>=768 -> m-768 (R_4^T left).
__global__ __launch_bounds__(256) void k_gemm_R(const u16* __restrict__ A,
                                                const u16* __restrict__ Ct,
                                                u16* __restrict__ Co,
                                                u16* __restrict__ CtT, int mode) {
  __shared__ __align__(16) u16 As[128 * 64];
  __shared__ __align__(16) u16 Bs[128 * 64];
  int bid = blockIdx.x;
  int nt = bid % 12, mt = bid / 12;
  int m0 = mt << 7, n0 = nt << 7;
  int tid = threadIdx.x, lane = tid & 63, wave = tid >> 6;
  int wm = (wave & 1) << 6, wn = (wave >> 1) << 6;
  f32x4 acc[4][4] = {};
  for (int kb = 0; kb < 24; ++kb) {
    stage128(A + m0 * 1536 + kb * 64, 1536, As);
    stage128(Ct + n0 * 1536 + kb * 64, 1536, Bs);
    __syncthreads();
    mfma_tile(As, Bs, lane, wm, wn, acc);
    __syncthreads();
  }
  int q = lane >> 4, cn = lane & 15;
  #pragma unroll
  for (int i = 0; i < 4; ++i)
    #pragma unroll
    for (int j = 0; j < 4; ++j) {
      int n = n0 + wn + j * 16 + cn;
      int mb = m0 + wm + i * 16 + q * 4;
      u16 pk[4];
      #pragma unroll
      for (int r = 0; r < 4; ++r) {
        u16 v = f2b(acc[i][j][r]);
        Co[(mb + r) * 1536 + n] = v;
        pk[r] = v;
      }
      if (mode) {
        int tcol = (mode == 1) ? mb : ((mb < 768) ? 768 + mb : mb - 768);
        *(uint2*)&CtT[n * 1536 + tcol] = *(uint2*)pk;
      }
    }
}

// H[t][o] = sum_{i<=t&7} U_i[o][:] . delta[t-i][:]  (delta read f32, cast on the fly)
__global__ __launch_bounds__(256) void k_conv(const float* __restrict__ delta,
                                              const u16* __restrict__ Rbig,
                                              float* __restrict__ Hbuf) {
  __shared__ __align__(16) u16 As[128 * 64];
  __shared__ __align__(16) u16 Bs[128 * 64];
  int bid = blockIdx.x;
  bid = (bid & 7) * 48 + (bid >> 3);    // XCD chunk swizzle (384/8 = 48)
  int nt = bid % 6, mt = (bid / 6) % 16, sp = bid / 96;
  int m0 = mt << 7, n0 = nt << 7;
  int tid = threadIdx.x, lane = tid & 63, wave = tid >> 6;
  int wm = (wave & 1) << 6, wn = (wave >> 1) << 6;
  int trow = tid >> 3, cb = tid & 7;
  f32x4 acc[4][4] = {};
  for (int kb = 0; kb < 24; ++kb) {
    int i = 2 * sp + kb / 12, dinb = kb % 12;
    #pragma unroll
    for (int s = 0; s < 4; ++s) {
      int row = trow + (s << 5);
      int t = m0 + row;
      u16 pk[8] = {0, 0, 0, 0, 0, 0, 0, 0};
      if (i <= (t & 7)) {
        const float* src = delta + (t - i) * 768 + dinb * 64 + (cb << 3);
        f32x4 v0 = *(const f32x4*)src;
        f32x4 v1 = *(const f32x4*)(src + 4);
        #pragma unroll
        for (int e = 0; e < 4; ++e) { pk[e] = f2b(v0[e]); pk[4 + e] = f2b(v1[e]); }
      }
      *(u32x4*)&As[row * 64 + ((cb ^ (row & 7)) << 3)] = *(u32x4*)pk;
    }
    stage128(Rbig + i * RJ + n0 * 1536 + dinb * 64, 1536, Bs);
    __syncthreads();
    mfma_tile(As, Bs, lane, wm, wn, acc);
    __syncthreads();
  }
  int q = lane >> 4, cn = lane & 15;
  #pragma unroll
  for (int i = 0; i < 4; ++i)
    #pragma unroll
    for (int j = 0; j < 4; ++j)
      #pragma unroll
      for (int r = 0; r < 4; ++r) {
        int m = m0 + wm + i * 16 + q * 4 + r;
        int n = n0 + wn + j * 16 + cn;
        unsafeAtomicAdd(&Hbuf[m * 768 + n], acc[i][j][r]);
      }
}

// warm round A: S[c] = J @ S0[c] + h(8c-9), where S0[c][q] = H[8c-17-(q>=768)][o]
// (A-operand staged from Hbuf on the fly).  J rows: n<768 -> R_8[n], else R_7[n-768].
__global__ __launch_bounds__(256) void k_scan_roundA(const u16* __restrict__ Rbig,
                                                     const float* __restrict__ Hbuf,
                                                     u16* __restrict__ Sout) {
  __shared__ __align__(16) u16 As[128 * 64];
  __shared__ __align__(16) u16 Bs[128 * 64];
  int bid = blockIdx.x;
  int nt = bid % 12, mt = bid / 12;
  int m0 = mt << 7, n0 = nt << 7;
  const u16* Bg = (nt < 6) ? (Rbig + 8 * RJ + n0 * 1536)
                           : (Rbig + 7 * RJ + (n0 - 768) * 1536);
  int tid = threadIdx.x, lane = tid & 63, wave = tid >> 6;
  int wm = (wave & 1) << 6, wn = (wave >> 1) << 6;
  int trow = tid >> 3, cb = tid & 7;
  f32x4 acc[4][4] = {};
  for (int kb = 0; kb < 24; ++kb) {
    #pragma unroll
    for (int s = 0; s < 4; ++s) {
      int row = trow + (s << 5);
      int c = m0 + row;
      int qb = kb * 64 + (cb << 3);
      int side = (qb >= 768) ? 1 : 0;
      int o0 = qb - side * 768;
      int t = 8 * c - 17 - side;
      u16 pk[8] = {0, 0, 0, 0, 0, 0, 0, 0};
      if (t >= 0) {
        const float* src = Hbuf + t * 768 + o0;
        f32x4 v0 = *(const f32x4*)src;
        f32x4 v1 = *(const f32x4*)(src + 4);
        #pragma unroll
        for (int e = 0; e < 4; ++e) { pk[e] = f2b(v0[e]); pk[4 + e] = f2b(v1[e]); }
      }
      *(u32x4*)&As[row * 64 + ((cb ^ (row & 7)) << 3)] = *(u32x4*)pk;
    }
    stage128(Bg + kb * 64, 1536, Bs);
    __syncthreads();
    mfma_tile(As, Bs, lane, wm, wn, acc);
    __syncthreads();
  }
  int q = lane >> 4, cn = lane & 15;
  #pragma unroll
  for (int i = 0; i < 4; ++i)
    #pragma unroll
    for (int j = 0; j < 4; ++j)
      #pragma unroll
      for (int r = 0; r < 4; ++r) {
        int c = m0 + wm + i * 16 + q * 4 + r;
        int n = n0 + wn + j * 16 + cn;
        int side = (n < 768) ? 0 : 1;
        int t = 8 * c - 9 - side;
        int o = n - side * 768;
        float val = acc[i][j][r] + ((t >= 0) ? Hbuf[t * 768 + o] : 0.f);
        Sout[c * 1536 + n] = f2b(val);
      }
}

// warm round B: Snew[c] = J @ Sin[c] + h(8c-1)
__global__ __launch_bounds__(256) void k_scan_round(const u16* __restrict__ Sin,
                                                    const u16* __restrict__ Rbig,
                                                    const float* __restrict__ Hbuf,
                                                    u16* __restrict__ Sout) {
  __shared__ __align__(16) u16 As[128 * 64];
  __shared__ __align__(16) u16 Bs[128 * 64];
  int bid = blockIdx.x;
  int nt = bid % 12, mt = bid / 12;
  int m0 = mt << 7, n0 = nt << 7;
  const u16* Bg = (nt < 6) ? (Rbig + 8 * RJ + n0 * 1536)
                           : (Rbig + 7 * RJ + (n0 - 768) * 1536);
  int tid = threadIdx.x, lane = tid & 63, wave = tid >> 6;
  int wm = (wave & 1) << 6, wn = (wave >> 1) << 6;
  f32x4 acc[4][4] = {};
  for (int kb = 0; kb < 24; ++kb) {
    stage128(Sin + m0 * 1536 + kb * 64, 1536, As);
    stage128(Bg + kb * 64, 1536, Bs);
    __syncthreads();
    mfma_tile(As, Bs, lane, wm, wn, acc);
    __syncthreads();
  }
  int q = lane >> 4, cn = lane & 15;
  #pragma unroll
  for (int i = 0; i < 4; ++i)
    #pragma unroll
    for (int j = 0; j < 4; ++j)
      #pragma unroll
      for (int r = 0; r < 4; ++r) {
        int c = m0 + wm + i * 16 + q * 4 + r;
        int n = n0 + wn + j * 16 + cn;
        int side = (n < 768) ? 0 : 1;
        int t = 8 * c - 1 - side;
        int o = n - side * 768;
        float val = acc[i][j][r] + ((t >= 0) ? Hbuf[t * 768 + o] : 0.f);
        Sout[c * 1536 + n] = f2b(val);
      }
}

// output: y[8c+jj] = (R_{jj+1} @ S[c])[o] + H[8c+jj][o]
__global__ __launch_bounds__(256) void k_scan_out(const u16* __restrict__ Sin,
                                                  const u16* __restrict__ Rbig,
                                                  const float* __restrict__ Hbuf,
                                                  float* __restrict__ out) {
  __shared__ __align__(16) u16 As[128 * 64];
  __shared__ __align__(16) u16 Bs[128 * 64];
  int bid = blockIdx.x;
  int nt = bid % 48, mt = bid / 48;
  int m0 = mt << 7, n0 = nt << 7;
  const u16* Bg = Rbig + RJ + n0 * 1536;   // rows of [R_1; ...; R_8]
  int tid = threadIdx.x, lane = tid & 63, wave = tid >> 6;
  int wm = (wave & 1) << 6, wn = (wave >> 1) << 6;
  f32x4 acc[4][4] = {};
  for (int kb = 0; kb < 24; ++kb) {
    stage128(Sin + m0 * 1536 + kb * 64, 1536, As);
    stage128(Bg + kb * 64, 1536, Bs);
    __syncthreads();
    mfma_tile(As, Bs, lane, wm, wn, acc);
    __syncthreads();
  }
  int q = lane >> 4, cn = lane & 15;
  #pragma unroll
  for (int i = 0; i < 4; ++i)
    #pragma unroll
    for (int j = 0; j < 4; ++j)
      #pragma unroll
      for (int r = 0; r < 4; ++r) {
        int c = m0 + wm + i * 16 + q * 4 + r;
        int n = n0 + wn + j * 16 + cn;
        int jj = n / 768, o = n % 768;
        int t = 8 * c + jj;
        out[t * 768 + o] = acc[i][j][r] + Hbuf[t * 768 + o];
      }
}

// ---------------------------------------------------------------------------
extern "C" void kernel_launch(void* const* d_in, const int* in_sizes, int n_in,
                              void* d_out, int out_size, void* d_ws, size_t ws_size,
                              hipStream_t stream) {
  const float* u    = (const float*)d_in[0];
  const float* my   = (const float*)d_in[1];
  const float* mu   = (const float*)d_in[2];
  const float* mphi = (const float*)d_in[3];
  const float* ev   = (const float*)d_in[4];
  const float* evec = (const float*)d_in[5];
  float* out = (float*)d_out;
  char* ws = (char*)d_ws;

  u16*   ub    = (u16*)(ws + WS_UB);
  u16*   mphiT = (u16*)(ws + WS_MPHIT);
  u16*   b2t   = (u16*)(ws + WS_B2T);
  u16*   tt    = (u16*)(ws + WS_TT);
  u16*   zt    = (u16*)(ws + WS_ZT);
  float* delta = (float*)(ws + WS_DELTA);
  u16*   Rbig  = (u16*)(ws + OV_RBIG);
  u16*   Ct0   = (u16*)(ws + OV_CT0);
  u16*   Ct1   = (u16*)(ws + OV_CT1);
  u16*   Ct2   = (u16*)(ws + OV_CT2);
  float* Hbuf  = (float*)(ws + OV_HBUF);
  u16*   SA    = (u16*)(ws + OV_SBUF);
  u16*   SB    = SA + 256 * 1536;

  hipLaunchKernelGGL(k_prep, dim3(59142), dim3(256), 0, stream,
                     u, mphi, ev, mu, evec, delta, ub, mphiT, b2t, tt);
  hipLaunchKernelGGL(k_gemm_zt,    dim3(1152), dim3(256), 0, stream,
                     mphiT, ub + 2 * 768, zt);
  hipLaunchKernelGGL(k_gemm_delta, dim3(432),  dim3(256), 0, stream,
                     tt, zt, ub, b2t, delta);

  // --- scan prep (overlays zt; stream-ordered after k_gemm_delta) ---
  hipLaunchKernelGGL(k_chain_init, dim3(24576), dim3(256), 0, stream,
                     my, Rbig, Ct0, Ct1, Hbuf);
  hipLaunchKernelGGL(k_gemm_R, dim3(72),  dim3(256), 0, stream,
                     Rbig + RJ, Ct0, Rbig + 2 * RJ, Ct1, 1);            // R_2
  hipLaunchKernelGGL(k_gemm_R, dim3(144), dim3(256), 0, stream,
                     Rbig + RJ, Ct1, Rbig + 3 * RJ, Ct2, 2);            // R_3,R_4
  hipLaunchKernelGGL(k_gemm_R, dim3(288), dim3(256), 0, stream,
                     Rbig + RJ, Ct2, Rbig + 5 * RJ, (u16*)nullptr, 0);  // R_5..R_8

  hipLaunchKernelGGL(k_conv, dim3(384), dim3(256), 0, stream, delta, Rbig, Hbuf);

  // --- scan: 2 warm-up jumps (A of round 1 staged from Hbuf) + output ---
  hipLaunchKernelGGL(k_scan_roundA, dim3(24), dim3(256), 0, stream, Rbig, Hbuf, SA);
  hipLaunchKernelGGL(k_scan_round,  dim3(24), dim3(256), 0, stream, SA, Rbig, Hbuf, SB);
  hipLaunchKernelGGL(k_scan_out,    dim3(96), dim3(256), 0, stream, SB, Rbig, Hbuf, out);
}

// Round 15
// 655.019 us; speedup vs baseline: 1.1877x; 1.1877x over previous
//
#include <hip/hip_runtime.h>
#include <hip/hip_bf16.h>
#include <stdint.h>

// STU forward: y = scan(m_y, (x_tilde @ m_phi) + AR(m_u, u))
// R5: 256x128 MFMA tiles for the two big GEMMs (32 MFMA per barrier-slab).
// R6: XCD-chunked blockIdx swizzle (T1) on k_gemm_zt / k_gemm_delta / k_conv.
// R9: revert of R7/R8 (verified 623.7 us base).
// R10: k_gemm_delta kk-split 2-way (grid 432 -> 864): each (db,a,s) block
// becomes two blocks h=0/1 handling kk in [12h,12h+12); AR tap kku done by
// owner with h==(kku&1). Raises blocks/CU 1.7 -> 3 (LDS cap) for inter-block
// TLP over the barrier drain. LDS/tile/epilogue unchanged.

typedef unsigned short u16;
typedef unsigned int   u32;
typedef __bf16  bf16x8 __attribute__((ext_vector_type(8)));
typedef float   f32x4  __attribute__((ext_vector_type(4)));
typedef u32     u32x4  __attribute__((ext_vector_type(4)));

#define MFMA(a,b,c) __builtin_amdgcn_mfma_f32_16x16x32_bf16(a,b,c,0,0,0)
#define RJ 1179648   // elems per R_j (768*1536)

__device__ __forceinline__ u16 f2b(float f) {           // fp32 -> bf16 bits, RNE
  union { float f; u32 u; } v; v.f = f;
  return (u16)((v.u + 0x7fffu + ((v.u >> 16) & 1u)) >> 16);
}

__device__ __forceinline__ void gld16(const u16* g, u16* l) {
  __builtin_amdgcn_global_load_lds(
      (const __attribute__((address_space(1))) u32*)g,
      (__attribute__((address_space(3))) u32*)l, 16, 0, 0);
}

// ---------------- workspace layout (bytes) ----------------
#define WS_UB     0            // [2050][768] bf16
#define WS_MPHIT  3148800      // [18432][768] bf16
#define WS_B2T    31460352     // [3][768][768] bf16
#define WS_TT     34999296     // [17][24][128][128] bf16 (slot 0 = delta-tile for dlt=-1, all zero)
#define WS_ZT     48368640     // [24][768][2048] bf16 (dead after k_gemm_delta)
#define WS_DELTA  123866112    // [2048][768] f32  (end 130157568)
// overlays inside zt region (phase 2, after k_gemm_delta):
#define OV_RBIG   (WS_ZT + 0)          // [9][768][1536] bf16
#define OV_CT0    (WS_ZT + 21233664)   // [1536][1536] bf16
#define OV_CT1    (WS_ZT + 25952256)
#define OV_CT2    (WS_ZT + 30670848)
#define OV_HBUF   (WS_ZT + 35389440)   // [2048][768] f32
#define OV_SBUF   (WS_ZT + 41680896)   // [2][256][1536] bf16

// ---------------------------------------------------------------------------
// k_prep: zero delta | repack u | repack mphi | repack mu | make_T  (one launch)
__global__ void k_prep(const float* __restrict__ u, const float* __restrict__ mphi,
                       const float* __restrict__ ev, const float* __restrict__ mu,
                       const float* __restrict__ evec,
                       float* __restrict__ delta, u16* __restrict__ ub,
                       u16* __restrict__ mphiT, u16* __restrict__ b2t,
                       u16* __restrict__ tt) {
  __shared__ float tile[32][33];
  int b = blockIdx.x, tid = threadIdx.x;
  if (b < 6144) {                       // zero delta
    delta[b * 256 + tid] = 0.f;
  } else if (b < 12294) {               // repack u (+2 guard rows)
    int i = (b - 6144) * 256 + tid;
    ub[i] = (i < 2 * 768) ? (u16)0 : f2b(u[i - 2 * 768]);
  } else if (b < 26118) {               // repack mphi (transpose per k, scale)
    int bid = b - 12294;
    int k = bid / 576, rem = bid % 576;
    int ti = rem / 24, tj = rem % 24;
    int c = tid & 31, r0 = tid >> 5;
    float s = powf(ev[k], 0.25f);
    #pragma unroll
    for (int rr = 0; rr < 4; ++rr) {
      int r = r0 + (rr << 3);
      tile[r][c] = mphi[(k * 768 + ti * 32 + r) * 768 + tj * 32 + c];
    }
    __syncthreads();
    #pragma unroll
    for (int rr = 0; rr < 4; ++rr) {
      int r = r0 + (rr << 3);
      mphiT[(k * 768 + tj * 32 + r) * 768 + ti * 32 + c] = f2b(tile[c][r] * s);
    }
  } else if (b < 33030) {               // repack mu
    int i = (b - 26118) * 256 + tid;
    int kk = i / (768 * 768);
    int rem = i % (768 * 768);
    int o = rem / 768, ii = rem % 768;
    b2t[i] = f2b(mu[(o * 768 + ii) * 3 + kk]);
  } else {                              // make_T (17 slots; slot 0 auto-zero)
    int i = (b - 33030) * 256 + tid;
    int c = i & 127, r = (i >> 7) & 127;
    int kk = (i >> 14) % 24, sl = (i >> 14) / 24;
    int t = (sl - 1) * 128 + r - c - 2;
    tt[i] = (t >= 0 && t < 2048) ? f2b(evec[t * 24 + kk]) : (u16)0;
  }
}

// ---------------------------------------------------------------------------
// Stage 128 rows x 64 u16 (16 KB) via async global_load_lds, XOR-swizzled:
// LDS slot (row, cb) holds global (row, cb ^ (row&7)).
__device__ __forceinline__ void stage128(const u16* __restrict__ g, int ld,
                                         u16* __restrict__ lds) {
  int tid = threadIdx.x;
  int r0 = tid >> 3, cb = tid & 7, wave = tid >> 6;
  #pragma unroll
  for (int s = 0; s < 4; ++s) {
    int row = r0 + (s << 5);
    int cbx = (cb ^ (row & 7)) << 3;
    gld16(g + row * ld + cbx, lds + (s << 11) + (wave << 9));
  }
}

// 128x128 tile MFMA over one K=64 slab (swizzle-aware reads).
__device__ __forceinline__ void mfma_tile(const u16* As, const u16* Bs, int lane,
                                          int wm, int wn, f32x4 acc[4][4]) {
  int cn = lane & 15, q = lane >> 4;
  #pragma unroll
  for (int ks = 0; ks < 2; ++ks) {
    int blk = ks * 4 + q;
    bf16x8 af[4], bg[4];
    #pragma unroll
    for (int i = 0; i < 4; ++i) {
      int row = wm + i * 16 + cn;
      af[i] = *(const bf16x8*)&As[row * 64 + ((blk ^ (row & 7)) << 3)];
    }
    #pragma unroll
    for (int j = 0; j < 4; ++j) {
      int row = wn + j * 16 + cn;
      bg[j] = *(const bf16x8*)&Bs[row * 64 + ((blk ^ (row & 7)) << 3)];
    }
    #pragma unroll
    for (int i = 0; i < 4; ++i)
      #pragma unroll
      for (int j = 0; j < 4; ++j)
        acc[i][j] = MFMA(af[i], bg[j], acc[i][j]);
  }
}

// 256x128 tile: wave owns 64 M-rows (wm = wave*64), all 128 N-cols. 32 MFMA/slab.
__device__ __forceinline__ void mfma_tile256(const u16* As, const u16* Bs, int lane,
                                             int wm, f32x4 acc[4][8]) {
  int cn = lane & 15, q = lane >> 4;
  #pragma unroll
  for (int ks = 0; ks < 2; ++ks) {
    int blk = ks * 4 + q;
    bf16x8 af[4], bg[8];
    #pragma unroll
    for (int i = 0; i < 4; ++i) {
      int row = wm + i * 16 + cn;
      af[i] = *(const bf16x8*)&As[row * 64 + ((blk ^ (row & 7)) << 3)];
    }
    #pragma unroll
    for (int j = 0; j < 8; ++j) {
      int row = j * 16 + cn;
      bg[j] = *(const bf16x8*)&Bs[row * 64 + ((blk ^ (row & 7)) << 3)];
    }
    #pragma unroll
    for (int i = 0; i < 4; ++i)
      #pragma unroll
      for (int j = 0; j < 8; ++j)
        acc[i][j] = MFMA(af[i], bg[j], acc[i][j]);
  }
}

// K2: Zt[18432 x 2048] = mphiT @ ub^T.  256x128 tiles, grid 72x16.
__global__ __launch_bounds__(256, 2) void k_gemm_zt(const u16* __restrict__ A,
                                                    const u16* __restrict__ B,
                                                    u16* __restrict__ C) {
  __shared__ __align__(16) u16 As[256 * 64];
  __shared__ __align__(16) u16 Bs[128 * 64];
  int bid = blockIdx.x;
  bid = (bid & 7) * 144 + (bid >> 3);   // XCD chunk swizzle (1152/8 = 144)
  int nt = bid & 15, mt = bid >> 4;
  int m0 = mt << 8, n0 = nt << 7;
  int tid = threadIdx.x, lane = tid & 63, wave = tid >> 6;
  int wm = wave << 6;
  f32x4 acc[4][8] = {};
  for (int kb = 0; kb < 12; ++kb) {
    stage128(A + m0 * 768 + kb * 64, 768, As);
    stage128(A + (m0 + 128) * 768 + kb * 64, 768, As + 8192);
    stage128(B + n0 * 768 + kb * 64, 768, Bs);
    __syncthreads();
    mfma_tile256(As, Bs, lane, wm, acc);
    __syncthreads();
  }
  int q = lane >> 4, cn = lane & 15;
  #pragma unroll
  for (int i = 0; i < 4; ++i)
    #pragma unroll
    for (int j = 0; j < 8; ++j)
      #pragma unroll
      for (int r = 0; r < 4; ++r) {
        int m = m0 + wm + i * 16 + q * 4 + r;
        int n = n0 + j * 16 + cn;
        C[m * 2048 + n] = f2b(acc[i][j][r]);
      }
}

// K3: delta = sum_k T_k @ Zt[k] + AR.  256x128 tiles; block = (db, a, s, h).
// Rows 0-127 of the A tile use dlt = 2a-s (slot dlt+1; slot 0 is all-zero),
// rows 128-255 use dlt = 2a+1-s.
// R10: kk-split 2-way: h = bid/432 selects kk in [12h, 12h+12); AR tap kku
// done by owner (s == min(kku,2a+1)) with h == (kku&1).
__global__ __launch_bounds__(256, 2) void k_gemm_delta(const u16* __restrict__ tt,
                                                       const u16* __restrict__ zt,
                                                       const u16* __restrict__ ub,
                                                       const u16* __restrict__ b2t,
                                                       float* __restrict__ delta) {
  __shared__ __align__(16) u16 As[256 * 64];
  __shared__ __align__(16) u16 Bs[128 * 64];
  int bid = blockIdx.x;
  int h = bid / 432;                    // kk-half
  int inner = bid % 432;
  inner = (inner % 8) * 54 + inner / 8; // XCD chunk swizzle (432/8 = 54)
  int db = inner % 6;
  int r2 = inner / 6;               // [0,72) -> (a, s), s in [0, 2a+2)
  int a = 0, s = 0;
  for (;; ++a) { int cnt = 2 * a + 2; if (r2 < cnt) { s = r2; break; } r2 -= cnt; }
  int n0 = db << 7;
  int tid = threadIdx.x, lane = tid & 63, wave = tid >> 6;
  int wm = wave << 6;
  f32x4 acc[4][8] = {};
  int d1 = 2 * a + 1 - s;                         // slot for lower half = d1+1
  const u16* A0 = tt + (size_t)d1 * 24 * 16384;         // slot d1 (= dlt0+1)
  const u16* A1 = tt + (size_t)(d1 + 1) * 24 * 16384;   // slot d1+1
  for (int kk = h * 12; kk < h * 12 + 12; ++kk) {
    const u16* Bg = zt + kk * (768 * 2048) + n0 * 2048 + s * 128;
    #pragma unroll
    for (int hf = 0; hf < 2; ++hf) {
      stage128(A0 + kk * 16384 + hf * 64, 128, As);
      stage128(A1 + kk * 16384 + hf * 64, 128, As + 8192);
      stage128(Bg + hf * 64, 2048, Bs);
      __syncthreads();
      mfma_tile256(As, Bs, lane, wm, acc);
      __syncthreads();
    }
  }
  // AR taps: tap kku owned by s == min(kku, 2a+1), half h == (kku & 1)
  #pragma unroll
  for (int kku = 0; kku < 3; ++kku) {
    int owner = (kku <= 2 * a + 1) ? kku : 2 * a + 1;
    if (s != owner || (kku & 1) != h) continue;
    const u16* Au = ub + (2 + a * 256 - kku) * 768;
    const u16* Bg = b2t + kku * (768 * 768) + n0 * 768;
    for (int ic = 0; ic < 12; ++ic) {
      stage128(Au + ic * 64, 768, As);
      stage128(Au + 128 * 768 + ic * 64, 768, As + 8192);
      stage128(Bg + ic * 64, 768, Bs);
      __syncthreads();
      mfma_tile256(As, Bs, lane, wm, acc);
      __syncthreads();
    }
  }
  int q = lane >> 4, cn = lane & 15;
  #pragma unroll
  for (int i = 0; i < 4; ++i)
    #pragma unroll
    for (int j = 0; j < 8; ++j)
      #pragma unroll
      for (int r = 0; r < 4; ++r) {
        int m = a * 256 + wm + i * 16 + q * 4 + r;
        int n = n0 + j * 16 + cn;
        unsafeAtomicAdd(&delta[m * 768 + n], acc[i][j][r]);
      }
}

// ---------------------------------------------------------------------------
// chain init: R_0=[I|0], R_1=[A1|A2], Ct0=[R_1;R_0]^T, Ct1 right half=R_1^T, zero H.
__global__ void k_chain_init(const float* __restrict__ my, u16* __restrict__ Rbig,
                             u16* __restrict__ Ct0, u16* __restrict__ Ct1,
                             float* __restrict__ Hbuf) {
  int b = blockIdx.x, tid = threadIdx.x;
  if (b < 4608) {                       // R_0, R_1
    int i = b * 256 + tid;
    int o = i / 1536, q = i % 1536;
    Rbig[i] = (q == o) ? (u16)0x3F80 : (u16)0;
    Rbig[RJ + i] = f2b(my[i]);
  } else if (b < 13824) {               // Ct0[n][p]
    int i = (b - 4608) * 256 + tid;
    int n = i / 1536, p = i % 1536;
    u16 v;
    if (p < 768) v = f2b(my[p * 1536 + n]);
    else         v = (p - 768 == n) ? (u16)0x3F80 : (u16)0;
    Ct0[i] = v;
  } else if (b < 18432) {               // Ct1[n][768+i] = R_1[i][n]
    int i = (b - 13824) * 256 + tid;
    int n = i / 768, ii = i % 768;
    Ct1[n * 1536 + 768 + ii] = f2b(my[ii * 1536 + n]);
  } else {                              // zero Hbuf
    int i = (b - 18432) * 256 + tid;
    Hbuf[i] = 0.f;
  }
}

// M x 1536 x 1536 GEMM (B = Ct, [n][k] layout). Dual epilogue: row-major out +
// optional transposed write into the next doubling's Ct.
// mode 0: none; 1: tcol=m (R_2^T -> left); 2: m<768 -> 768+m (R_3^T right),
// m>=768 -> m-768 (R_4^T left).
__global__ __launch_bounds__(256) void k_gemm_R(const u16* __restrict__ A,
                                                const u16* __restrict__ Ct,
                                                u16* __restrict__ Co,
                                                u16* __restrict__ CtT, int mode) {
  __shared__ __align__(16) u16 As[128 * 64];
  __shared__ __align__(16) u16 Bs[128 * 64];
  int bid = blockIdx.x;
  int nt = bid % 12, mt = bid / 12;
  int m0 = mt << 7, n0 = nt << 7;
  int tid = threadIdx.x, lane = tid & 63, wave = tid >> 6;
  int wm = (wave & 1) << 6, wn = (wave >> 1) << 6;
  f32x4 acc[4][4] = {};
  for (int kb = 0; kb < 24; ++kb) {
    stage128(A + m0 * 1536 + kb * 64, 1536, As);
    stage128(Ct + n0 * 1536 + kb * 64, 1536, Bs);
    __syncthreads();
    mfma_tile(As, Bs, lane, wm, wn, acc);
    __syncthreads();
  }
  int q = lane >> 4, cn = lane & 15;
  #pragma unroll
  for (int i = 0; i < 4; ++i)
    #pragma unroll
    for (int j = 0; j < 4; ++j) {
      int n = n0 + wn + j * 16 + cn;
      int mb = m0 + wm + i * 16 + q * 4;
      u16 pk[4];
      #pragma unroll
      for (int r = 0; r < 4; ++r) {
        u16 v = f2b(acc[i][j][r]);
        Co[(mb + r) * 1536 + n] = v;
        pk[r] = v;
      }
      if (mode) {
        int tcol = (mode == 1) ? mb : ((mb < 768) ? 768 + mb : mb - 768);
        *(uint2*)&CtT[n * 1536 + tcol] = *(uint2*)pk;
      }
    }
}

// H[t][o] = sum_{i<=t&7} U_i[o][:] . delta[t-i][:]  (delta read f32, cast on the fly)
__global__ __launch_bounds__(256) void k_conv(const float* __restrict__ delta,
                                              const u16* __restrict__ Rbig,
                                              float* __restrict__ Hbuf) {
  __shared__ __align__(16) u16 As[128 * 64];
  __shared__ __align__(16) u16 Bs[128 * 64];
  int bid = blockIdx.x;
  bid = (bid & 7) * 48 + (bid >> 3);    // XCD chunk swizzle (384/8 = 48)
  int nt = bid % 6, mt = (bid / 6) % 16, sp = bid / 96;
  int m0 = mt << 7, n0 = nt << 7;
  int tid = threadIdx.x, lane = tid & 63, wave = tid >> 6;
  int wm = (wave & 1) << 6, wn = (wave >> 1) << 6;
  int trow = tid >> 3, cb = tid & 7;
  f32x4 acc[4][4] = {};
  for (int kb = 0; kb < 24; ++kb) {
    int i = 2 * sp + kb / 12, dinb = kb % 12;
    #pragma unroll
    for (int s = 0; s < 4; ++s) {
      int row = trow + (s << 5);
      int t = m0 + row;
      u16 pk[8] = {0, 0, 0, 0, 0, 0, 0, 0};
      if (i <= (t & 7)) {
        const float* src = delta + (t - i) * 768 + dinb * 64 + (cb << 3);
        f32x4 v0 = *(const f32x4*)src;
        f32x4 v1 = *(const f32x4*)(src + 4);
        #pragma unroll
        for (int e = 0; e < 4; ++e) { pk[e] = f2b(v0[e]); pk[4 + e] = f2b(v1[e]); }
      }
      *(u32x4*)&As[row * 64 + ((cb ^ (row & 7)) << 3)] = *(u32x4*)pk;
    }
    stage128(Rbig + i * RJ + n0 * 1536 + dinb * 64, 1536, Bs);
    __syncthreads();
    mfma_tile(As, Bs, lane, wm, wn, acc);
    __syncthreads();
  }
  int q = lane >> 4, cn = lane & 15;
  #pragma unroll
  for (int i = 0; i < 4; ++i)
    #pragma unroll
    for (int j = 0; j < 4; ++j)
      #pragma unroll
      for (int r = 0; r < 4; ++r) {
        int m = m0 + wm + i * 16 + q * 4 + r;
        int n = n0 + wn + j * 16 + cn;
        unsafeAtomicAdd(&Hbuf[m * 768 + n], acc[i][j][r]);
      }
}

// warm round A: S[c] = J @ S0[c] + h(8c-9), where S0[c][q] = H[8c-17-(q>=768)][o]
// (A-operand staged from Hbuf on the fly).  J rows: n<768 -> R_8[n], else R_7[n-768].
__global__ __launch_bounds__(256) void k_scan_roundA(const u16* __restrict__ Rbig,
                                                     const float* __restrict__ Hbuf,
                                                     u16* __restrict__ Sout) {
  __shared__ __align__(16) u16 As[128 * 64];
  __shared__ __align__(16) u16 Bs[128 * 64];
  int bid = blockIdx.x;
  int nt = bid % 12, mt = bid / 12;
  int m0 = mt << 7, n0 = nt << 7;
  const u16* Bg = (nt < 6) ? (Rbig + 8 * RJ + n0 * 1536)
                           : (Rbig + 7 * RJ + (n0 - 768) * 1536);
  int tid = threadIdx.x, lane = tid & 63, wave = tid >> 6;
  int wm = (wave & 1) << 6, wn = (wave >> 1) << 6;
  int trow = tid >> 3, cb = tid & 7;
  f32x4 acc[4][4] = {};
  for (int kb = 0; kb < 24; ++kb) {
    #pragma unroll
    for (int s = 0; s < 4; ++s) {
      int row = trow + (s << 5);
      int c = m0 + row;
      int qb = kb * 64 + (cb << 3);
      int side = (qb >= 768) ? 1 : 0;
      int o0 = qb - side * 768;
      int t = 8 * c - 17 - side;
      u16 pk[8] = {0, 0, 0, 0, 0, 0, 0, 0};
      if (t >= 0) {
        const float* src = Hbuf + t * 768 + o0;
        f32x4 v0 = *(const f32x4*)src;
        f32x4 v1 = *(const f32x4*)(src + 4);
        #pragma unroll
        for (int e = 0; e < 4; ++e) { pk[e] = f2b(v0[e]); pk[4 + e] = f2b(v1[e]); }
      }
      *(u32x4*)&As[row * 64 + ((cb ^ (row & 7)) << 3)] = *(u32x4*)pk;
    }
    stage128(Bg + kb * 64, 1536, Bs);
    __syncthreads();
    mfma_tile(As, Bs, lane, wm, wn, acc);
    __syncthreads();
  }
  int q = lane >> 4, cn = lane & 15;
  #pragma unroll
  for (int i = 0; i < 4; ++i)
    #pragma unroll
    for (int j = 0; j < 4; ++j)
      #pragma unroll
      for (int r = 0; r < 4; ++r) {
        int c = m0 + wm + i * 16 + q * 4 + r;
        int n = n0 + wn + j * 16 + cn;
        int side = (n < 768) ? 0 : 1;
        int t = 8 * c - 9 - side;
        int o = n - side * 768;
        float val = acc[i][j][r] + ((t >= 0) ? Hbuf[t * 768 + o] : 0.f);
        Sout[c * 1536 + n] = f2b(val);
      }
}

// warm round B: Snew[c] = J @ Sin[c] + h(8c-1)
__global__ __launch_bounds__(256) void k_scan_round(const u16* __restrict__ Sin,
                                                    const u16* __restrict__ Rbig,
                                                    const float* __restrict__ Hbuf,
                                                    u16* __restrict__ Sout) {
  __shared__ __align__(16) u16 As[128 * 64];
  __shared__ __align__(16) u16 Bs[128 * 64];
  int bid = blockIdx.x;
  int nt = bid % 12, mt = bid / 12;
  int m0 = mt << 7, n0 = nt << 7;
  const u16* Bg = (nt < 6) ? (Rbig + 8 * RJ + n0 * 1536)
                           : (Rbig + 7 * RJ + (n0 - 768) * 1536);
  int tid = threadIdx.x, lane = tid & 63, wave = tid >> 6;
  int wm = (wave & 1) << 6, wn = (wave >> 1) << 6;
  f32x4 acc[4][4] = {};
  for (int kb = 0; kb < 24; ++kb) {
    stage128(Sin + m0 * 1536 + kb * 64, 1536, As);
    stage128(Bg + kb * 64, 1536, Bs);
    __syncthreads();
    mfma_tile(As, Bs, lane, wm, wn, acc);
    __syncthreads();
  }
  int q = lane >> 4, cn = lane & 15;
  #pragma unroll
  for (int i = 0; i < 4; ++i)
    #pragma unroll
    for (int j = 0; j < 4; ++j)
      #pragma unroll
      for (int r = 0; r < 4; ++r) {
        int c = m0 + wm + i * 16 + q * 4 + r;
        int n = n0 + wn + j * 16 + cn;
        int side = (n < 768) ? 0 : 1;
        int t = 8 * c - 1 - side;
        int o = n - side * 768;
        float val = acc[i][j][r] + ((t >= 0) ? Hbuf[t * 768 + o] : 0.f);
        Sout[c * 1536 + n] = f2b(val);
      }
}

// output: y[8c+jj] = (R_{jj+1} @ S[c])[o] + H[8c+jj][o]
__global__ __launch_bounds__(256) void k_scan_out(const u16* __restrict__ Sin,
                                                  const u16* __restrict__ Rbig,
                                                  const float* __restrict__ Hbuf,
                                                  float* __restrict__ out) {
  __shared__ __align__(16) u16 As[128 * 64];
  __shared__ __align__(16) u16 Bs[128 * 64];
  int bid = blockIdx.x;
  int nt = bid % 48, mt = bid / 48;
  int m0 = mt << 7, n0 = nt << 7;
  const u16* Bg = Rbig + RJ + n0 * 1536;   // rows of [R_1; ...; R_8]
  int tid = threadIdx.x, lane = tid & 63, wave = tid >> 6;
  int wm = (wave & 1) << 6, wn = (wave >> 1) << 6;
  f32x4 acc[4][4] = {};
  for (int kb = 0; kb < 24; ++kb) {
    stage128(Sin + m0 * 1536 + kb * 64, 1536, As);
    stage128(Bg + kb * 64, 1536, Bs);
    __syncthreads();
    mfma_tile(As, Bs, lane, wm, wn, acc);
    __syncthreads();
  }
  int q = lane >> 4, cn = lane & 15;
  #pragma unroll
  for (int i = 0; i < 4; ++i)
    #pragma unroll
    for (int j = 0; j < 4; ++j)
      #pragma unroll
      for (int r = 0; r < 4; ++r) {
        int c = m0 + wm + i * 16 + q * 4 + r;
        int n = n0 + wn + j * 16 + cn;
        int jj = n / 768, o = n % 768;
        int t = 8 * c + jj;
        out[t * 768 + o] = acc[i][j][r] + Hbuf[t * 768 + o];
      }
}

// ---------------------------------------------------------------------------
extern "C" void kernel_launch(void* const* d_in, const int* in_sizes, int n_in,
                              void* d_out, int out_size, void* d_ws, size_t ws_size,
                              hipStream_t stream) {
  const float* u    = (const float*)d_in[0];
  const float* my   = (const float*)d_in[1];
  const float* mu   = (const float*)d_in[2];
  const float* mphi = (const float*)d_in[3];
  const float* ev   = (const float*)d_in[4];
  const float* evec = (const float*)d_in[5];
  float* out = (float*)d_out;
  char* ws = (char*)d_ws;

  u16*   ub    = (u16*)(ws + WS_UB);
  u16*   mphiT = (u16*)(ws + WS_MPHIT);
  u16*   b2t   = (u16*)(ws + WS_B2T);
  u16*   tt    = (u16*)(ws + WS_TT);
  u16*   zt    = (u16*)(ws + WS_ZT);
  float* delta = (float*)(ws + WS_DELTA);
  u16*   Rbig  = (u16*)(ws + OV_RBIG);
  u16*   Ct0   = (u16*)(ws + OV_CT0);
  u16*   Ct1   = (u16*)(ws + OV_CT1);
  u16*   Ct2   = (u16*)(ws + OV_CT2);
  float* Hbuf  = (float*)(ws + OV_HBUF);
  u16*   SA    = (u16*)(ws + OV_SBUF);
  u16*   SB    = SA + 256 * 1536;

  hipLaunchKernelGGL(k_prep, dim3(59142), dim3(256), 0, stream,
                     u, mphi, ev, mu, evec, delta, ub, mphiT, b2t, tt);
  hipLaunchKernelGGL(k_gemm_zt,    dim3(1152), dim3(256), 0, stream,
                     mphiT, ub + 2 * 768, zt);
  hipLaunchKernelGGL(k_gemm_delta, dim3(864),  dim3(256), 0, stream,
                     tt, zt, ub, b2t, delta);

  // --- scan prep (overlays zt; stream-ordered after k_gemm_delta) ---
  hipLaunchKernelGGL(k_chain_init, dim3(24576), dim3(256), 0, stream,
                     my, Rbig, Ct0, Ct1, Hbuf);
  hipLaunchKernelGGL(k_gemm_R, dim3(72),  dim3(256), 0, stream,
                     Rbig + RJ, Ct0, Rbig + 2 * RJ, Ct1, 1);            // R_2
  hipLaunchKernelGGL(k_gemm_R, dim3(144), dim3(256), 0, stream,
                     Rbig + RJ, Ct1, Rbig + 3 * RJ, Ct2, 2);            // R_3,R_4
  hipLaunchKernelGGL(k_gemm_R, dim3(288), dim3(256), 0, stream,
                     Rbig + RJ, Ct2, Rbig + 5 * RJ, (u16*)nullptr, 0);  // R_5..R_8

  hipLaunchKernelGGL(k_conv, dim3(384), dim3(256), 0, stream, delta, Rbig, Hbuf);

  // --- scan: 2 warm-up jumps (A of round 1 staged from Hbuf) + output ---
  hipLaunchKernelGGL(k_scan_roundA, dim3(24), dim3(256), 0, stream, Rbig, Hbuf, SA);
  hipLaunchKernelGGL(k_scan_round,  dim3(24), dim3(256), 0, stream, SA, Rbig, Hbuf, SB);
  hipLaunchKernelGGL(k_scan_out,    dim3(96), dim3(256), 0, stream, SB, Rbig, Hbuf, out);
}

// Round 18
// 622.025 us; speedup vs baseline: 1.2507x; 1.0530x over previous
//
#include <hip/hip_runtime.h>
#include <hip/hip_bf16.h>
#include <stdint.h>

// STU forward: y = scan(m_y, (x_tilde @ m_phi) + AR(m_u, u))
// R5: 256x128 MFMA tiles for the two big GEMMs (32 MFMA per barrier-slab).
// R6: XCD-chunked blockIdx swizzle (T1) on k_gemm_zt / k_gemm_delta / k_conv.
// R11: FINAL revert to the verified 623.7 us configuration (R6). Ledger:
//   R7  s-major enum:   FETCH 188->84 MB but dur +4% (not BW-bound).
//   R8  dbuf pipeline:  -74% (96KB LDS -> 1 blk/CU; drain-0 prefetch null).
//   R10 kk-split 2-way: -24% (occupancy unmoved; atomic epilogue doubled,
//       +55MB writes = +27us -- atomics are ~21% of this kernel).
// Remaining lever is the 8-phase counted-vmcnt rewrite (high-risk template).

typedef unsigned short u16;
typedef unsigned int   u32;
typedef __bf16  bf16x8 __attribute__((ext_vector_type(8)));
typedef float   f32x4  __attribute__((ext_vector_type(4)));
typedef u32     u32x4  __attribute__((ext_vector_type(4)));

#define MFMA(a,b,c) __builtin_amdgcn_mfma_f32_16x16x32_bf16(a,b,c,0,0,0)
#define RJ 1179648   // elems per R_j (768*1536)

__device__ __forceinline__ u16 f2b(float f) {           // fp32 -> bf16 bits, RNE
  union { float f; u32 u; } v; v.f = f;
  return (u16)((v.u + 0x7fffu + ((v.u >> 16) & 1u)) >> 16);
}

__device__ __forceinline__ void gld16(const u16* g, u16* l) {
  __builtin_amdgcn_global_load_lds(
      (const __attribute__((address_space(1))) u32*)g,
      (__attribute__((address_space(3))) u32*)l, 16, 0, 0);
}

// ---------------- workspace layout (bytes) ----------------
#define WS_UB     0            // [2050][768] bf16
#define WS_MPHIT  3148800      // [18432][768] bf16
#define WS_B2T    31460352     // [3][768][768] bf16
#define WS_TT     34999296     // [17][24][128][128] bf16 (slot 0 = delta-tile for dlt=-1, all zero)
#define WS_ZT     48368640     // [24][768][2048] bf16 (dead after k_gemm_delta)
#define WS_DELTA  123866112    // [2048][768] f32  (end 130157568)
// overlays inside zt region (phase 2, after k_gemm_delta):
#define OV_RBIG   (WS_ZT + 0)          // [9][768][1536] bf16
#define OV_CT0    (WS_ZT + 21233664)   // [1536][1536] bf16
#define OV_CT1    (WS_ZT + 25952256)
#define OV_CT2    (WS_ZT + 30670848)
#define OV_HBUF   (WS_ZT + 35389440)   // [2048][768] f32
#define OV_SBUF   (WS_ZT + 41680896)   // [2][256][1536] bf16

// ---------------------------------------------------------------------------
// k_prep: zero delta | repack u | repack mphi | repack mu | make_T  (one launch)
__global__ void k_prep(const float* __restrict__ u, const float* __restrict__ mphi,
                       const float* __restrict__ ev, const float* __restrict__ mu,
                       const float* __restrict__ evec,
                       float* __restrict__ delta, u16* __restrict__ ub,
                       u16* __restrict__ mphiT, u16* __restrict__ b2t,
                       u16* __restrict__ tt) {
  __shared__ float tile[32][33];
  int b = blockIdx.x, tid = threadIdx.x;
  if (b < 6144) {                       // zero delta
    delta[b * 256 + tid] = 0.f;
  } else if (b < 12294) {               // repack u (+2 guard rows)
    int i = (b - 6144) * 256 + tid;
    ub[i] = (i < 2 * 768) ? (u16)0 : f2b(u[i - 2 * 768]);
  } else if (b < 26118) {               // repack mphi (transpose per k, scale)
    int bid = b - 12294;
    int k = bid / 576, rem = bid % 576;
    int ti = rem / 24, tj = rem % 24;
    int c = tid & 31, r0 = tid >> 5;
    float s = powf(ev[k], 0.25f);
    #pragma unroll
    for (int rr = 0; rr < 4; ++rr) {
      int r = r0 + (rr << 3);
      tile[r][c] = mphi[(k * 768 + ti * 32 + r) * 768 + tj * 32 + c];
    }
    __syncthreads();
    #pragma unroll
    for (int rr = 0; rr < 4; ++rr) {
      int r = r0 + (rr << 3);
      mphiT[(k * 768 + tj * 32 + r) * 768 + ti * 32 + c] = f2b(tile[c][r] * s);
    }
  } else if (b < 33030) {               // repack mu
    int i = (b - 26118) * 256 + tid;
    int kk = i / (768 * 768);
    int rem = i % (768 * 768);
    int o = rem / 768, ii = rem % 768;
    b2t[i] = f2b(mu[(o * 768 + ii) * 3 + kk]);
  } else {                              // make_T (17 slots; slot 0 auto-zero)
    int i = (b - 33030) * 256 + tid;
    int c = i & 127, r = (i >> 7) & 127;
    int kk = (i >> 14) % 24, sl = (i >> 14) / 24;
    int t = (sl - 1) * 128 + r - c - 2;
    tt[i] = (t >= 0 && t < 2048) ? f2b(evec[t * 24 + kk]) : (u16)0;
  }
}

// ---------------------------------------------------------------------------
// Stage 128 rows x 64 u16 (16 KB) via async global_load_lds, XOR-swizzled:
// LDS slot (row, cb) holds global (row, cb ^ (row&7)).
__device__ __forceinline__ void stage128(const u16* __restrict__ g, int ld,
                                         u16* __restrict__ lds) {
  int tid = threadIdx.x;
  int r0 = tid >> 3, cb = tid & 7, wave = tid >> 6;
  #pragma unroll
  for (int s = 0; s < 4; ++s) {
    int row = r0 + (s << 5);
    int cbx = (cb ^ (row & 7)) << 3;
    gld16(g + row * ld + cbx, lds + (s << 11) + (wave << 9));
  }
}

// 128x128 tile MFMA over one K=64 slab (swizzle-aware reads).
__device__ __forceinline__ void mfma_tile(const u16* As, const u16* Bs, int lane,
                                          int wm, int wn, f32x4 acc[4][4]) {
  int cn = lane & 15, q = lane >> 4;
  #pragma unroll
  for (int ks = 0; ks < 2; ++ks) {
    int blk = ks * 4 + q;
    bf16x8 af[4], bg[4];
    #pragma unroll
    for (int i = 0; i < 4; ++i) {
      int row = wm + i * 16 + cn;
      af[i] = *(const bf16x8*)&As[row * 64 + ((blk ^ (row & 7)) << 3)];
    }
    #pragma unroll
    for (int j = 0; j < 4; ++j) {
      int row = wn + j * 16 + cn;
      bg[j] = *(const bf16x8*)&Bs[row * 64 + ((blk ^ (row & 7)) << 3)];
    }
    #pragma unroll
    for (int i = 0; i < 4; ++i)
      #pragma unroll
      for (int j = 0; j < 4; ++j)
        acc[i][j] = MFMA(af[i], bg[j], acc[i][j]);
  }
}

// 256x128 tile: wave owns 64 M-rows (wm = wave*64), all 128 N-cols. 32 MFMA/slab.
__device__ __forceinline__ void mfma_tile256(const u16* As, const u16* Bs, int lane,
                                             int wm, f32x4 acc[4][8]) {
  int cn = lane & 15, q = lane >> 4;
  #pragma unroll
  for (int ks = 0; ks < 2; ++ks) {
    int blk = ks * 4 + q;
    bf16x8 af[4], bg[8];
    #pragma unroll
    for (int i = 0; i < 4; ++i) {
      int row = wm + i * 16 + cn;
      af[i] = *(const bf16x8*)&As[row * 64 + ((blk ^ (row & 7)) << 3)];
    }
    #pragma unroll
    for (int j = 0; j < 8; ++j) {
      int row = j * 16 + cn;
      bg[j] = *(const bf16x8*)&Bs[row * 64 + ((blk ^ (row & 7)) << 3)];
    }
    #pragma unroll
    for (int i = 0; i < 4; ++i)
      #pragma unroll
      for (int j = 0; j < 8; ++j)
        acc[i][j] = MFMA(af[i], bg[j], acc[i][j]);
  }
}

// K2: Zt[18432 x 2048] = mphiT @ ub^T.  256x128 tiles, grid 72x16.
__global__ __launch_bounds__(256, 2) void k_gemm_zt(const u16* __restrict__ A,
                                                    const u16* __restrict__ B,
                                                    u16* __restrict__ C) {
  __shared__ __align__(16) u16 As[256 * 64];
  __shared__ __align__(16) u16 Bs[128 * 64];
  int bid = blockIdx.x;
  bid = (bid & 7) * 144 + (bid >> 3);   // XCD chunk swizzle (1152/8 = 144)
  int nt = bid & 15, mt = bid >> 4;
  int m0 = mt << 8, n0 = nt << 7;
  int tid = threadIdx.x, lane = tid & 63, wave = tid >> 6;
  int wm = wave << 6;
  f32x4 acc[4][8] = {};
  for (int kb = 0; kb < 12; ++kb) {
    stage128(A + m0 * 768 + kb * 64, 768, As);
    stage128(A + (m0 + 128) * 768 + kb * 64, 768, As + 8192);
    stage128(B + n0 * 768 + kb * 64, 768, Bs);
    __syncthreads();
    mfma_tile256(As, Bs, lane, wm, acc);
    __syncthreads();
  }
  int q = lane >> 4, cn = lane & 15;
  #pragma unroll
  for (int i = 0; i < 4; ++i)
    #pragma unroll
    for (int j = 0; j < 8; ++j)
      #pragma unroll
      for (int r = 0; r < 4; ++r) {
        int m = m0 + wm + i * 16 + q * 4 + r;
        int n = n0 + j * 16 + cn;
        C[m * 2048 + n] = f2b(acc[i][j][r]);
      }
}

// K3: delta = sum_k T_k @ Zt[k] + AR.  256x128 tiles; block = (db, a, s).
// Rows 0-127 of the A tile use dlt = 2a-s (slot dlt+1; slot 0 is all-zero),
// rows 128-255 use dlt = 2a+1-s.
__global__ __launch_bounds__(256, 2) void k_gemm_delta(const u16* __restrict__ tt,
                                                       const u16* __restrict__ zt,
                                                       const u16* __restrict__ ub,
                                                       const u16* __restrict__ b2t,
                                                       float* __restrict__ delta) {
  __shared__ __align__(16) u16 As[256 * 64];
  __shared__ __align__(16) u16 Bs[128 * 64];
  int bid = blockIdx.x;
  bid = (bid % 8) * 54 + bid / 8;       // XCD chunk swizzle (432/8 = 54)
  int db = bid % 6;
  int r2 = bid / 6;                 // [0,72) -> (a, s), s in [0, 2a+2)
  int a = 0, s = 0;
  for (;; ++a) { int cnt = 2 * a + 2; if (r2 < cnt) { s = r2; break; } r2 -= cnt; }
  int n0 = db << 7;
  int tid = threadIdx.x, lane = tid & 63, wave = tid >> 6;
  int wm = wave << 6;
  f32x4 acc[4][8] = {};
  int d1 = 2 * a + 1 - s;                         // slot for lower half = d1+1
  const u16* A0 = tt + (size_t)d1 * 24 * 16384;         // slot d1 (= dlt0+1)
  const u16* A1 = tt + (size_t)(d1 + 1) * 24 * 16384;   // slot d1+1
  for (int kk = 0; kk < 24; ++kk) {
    const u16* Bg = zt + kk * (768 * 2048) + n0 * 2048 + s * 128;
    #pragma unroll
    for (int hf = 0; hf < 2; ++hf) {
      stage128(A0 + kk * 16384 + hf * 64, 128, As);
      stage128(A1 + kk * 16384 + hf * 64, 128, As + 8192);
      stage128(Bg + hf * 64, 2048, Bs);
      __syncthreads();
      mfma_tile256(As, Bs, lane, wm, acc);
      __syncthreads();
    }
  }
  // AR taps: tap kku owned by s == min(kku, 2a+1)
  #pragma unroll
  for (int kku = 0; kku < 3; ++kku) {
    int owner = (kku <= 2 * a + 1) ? kku : 2 * a + 1;
    if (s != owner) continue;
    const u16* Au = ub + (2 + a * 256 - kku) * 768;
    const u16* Bg = b2t + kku * (768 * 768) + n0 * 768;
    for (int ic = 0; ic < 12; ++ic) {
      stage128(Au + ic * 64, 768, As);
      stage128(Au + 128 * 768 + ic * 64, 768, As + 8192);
      stage128(Bg + ic * 64, 768, Bs);
      __syncthreads();
      mfma_tile256(As, Bs, lane, wm, acc);
      __syncthreads();
    }
  }
  int q = lane >> 4, cn = lane & 15;
  #pragma unroll
  for (int i = 0; i < 4; ++i)
    #pragma unroll
    for (int j = 0; j < 8; ++j)
      #pragma unroll
      for (int r = 0; r < 4; ++r) {
        int m = a * 256 + wm + i * 16 + q * 4 + r;
        int n = n0 + j * 16 + cn;
        unsafeAtomicAdd(&delta[m * 768 + n], acc[i][j][r]);
      }
}

// ---------------------------------------------------------------------------
// chain init: R_0=[I|0], R_1=[A1|A2], Ct0=[R_1;R_0]^T, Ct1 right half=R_1^T, zero H.
__global__ void k_chain_init(const float* __restrict__ my, u16* __restrict__ Rbig,
                             u16* __restrict__ Ct0, u16* __restrict__ Ct1,
                             float* __restrict__ Hbuf) {
  int b = blockIdx.x, tid = threadIdx.x;
  if (b < 4608) {                       // R_0, R_1
    int i = b * 256 + tid;
    int o = i / 1536, q = i % 1536;
    Rbig[i] = (q == o) ? (u16)0x3F80 : (u16)0;
    Rbig[RJ + i] = f2b(my[i]);
  } else if (b < 13824) {               // Ct0[n][p]
    int i = (b - 4608) * 256 + tid;
    int n = i / 1536, p = i % 1536;
    u16 v;
    if (p < 768) v = f2b(my[p * 1536 + n]);
    else         v = (p - 768 == n) ? (u16)0x3F80 : (u16)0;
    Ct0[i] = v;
  } else if (b < 18432) {               // Ct1[n][768+i] = R_1[i][n]
    int i = (b - 13824) * 256 + tid;
    int n = i / 768, ii = i % 768;
    Ct1[n * 1536 + 768 + ii] = f2b(my[ii * 1536 + n]);
  } else {                              // zero Hbuf
    int i = (b - 18432) * 256 + tid;
    Hbuf[i] = 0.f;
  }
}

// M x 1536 x 1536 GEMM (B = Ct, [n][k] layout). Dual epilogue: row-major out +
// optional transposed write into the next doubling's Ct.
// mode 0: none; 1: tcol=m (R_2^T -> left); 2: m<768 -> 768+m (R_3^T right),
// m>=768 -> m-768 (R_4^T left).
__global__ __launch_bounds__(256) void k_gemm_R(const u16* __restrict__ A,
                                                const u16* __restrict__ Ct,
                                                u16* __restrict__ Co,
                                                u16* __restrict__ CtT, int mode) {
  __shared__ __align__(16) u16 As[128 * 64];
  __shared__ __align__(16) u16 Bs[128 * 64];
  int bid = blockIdx.x;
  int nt = bid % 12, mt = bid / 12;
  int m0 = mt << 7, n0 = nt << 7;
  int tid = threadIdx.x, lane = tid & 63, wave = tid >> 6;
  int wm = (wave & 1) << 6, wn = (wave >> 1) << 6;
  f32x4 acc[4][4] = {};
  for (int kb = 0; kb < 24; ++kb) {
    stage128(A + m0 * 1536 + kb * 64, 1536, As);
    stage128(Ct + n0 * 1536 + kb * 64, 1536, Bs);
    __syncthreads();
    mfma_tile(As, Bs, lane, wm, wn, acc);
    __syncthreads();
  }
  int q = lane >> 4, cn = lane & 15;
  #pragma unroll
  for (int i = 0; i < 4; ++i)
    #pragma unroll
    for (int j = 0; j < 4; ++j) {
      int n = n0 + wn + j * 16 + cn;
      int mb = m0 + wm + i * 16 + q * 4;
      u16 pk[4];
      #pragma unroll
      for (int r = 0; r < 4; ++r) {
        u16 v = f2b(acc[i][j][r]);
        Co[(mb + r) * 1536 + n] = v;
        pk[r] = v;
      }
      if (mode) {
        int tcol = (mode == 1) ? mb : ((mb < 768) ? 768 + mb : mb - 768);
        *(uint2*)&CtT[n * 1536 + tcol] = *(uint2*)pk;
      }
    }
}

// H[t][o] = sum_{i<=t&7} U_i[o][:] . delta[t-i][:]  (delta read f32, cast on the fly)
__global__ __launch_bounds__(256) void k_conv(const float* __restrict__ delta,
                                              const u16* __restrict__ Rbig,
                                              float* __restrict__ Hbuf) {
  __shared__ __align__(16) u16 As[128 * 64];
  __shared__ __align__(16) u16 Bs[128 * 64];
  int bid = blockIdx.x;
  bid = (bid & 7) * 48 + (bid >> 3);    // XCD chunk swizzle (384/8 = 48)
  int nt = bid % 6, mt = (bid / 6) % 16, sp = bid / 96;
  int m0 = mt << 7, n0 = nt << 7;
  int tid = threadIdx.x, lane = tid & 63, wave = tid >> 6;
  int wm = (wave & 1) << 6, wn = (wave >> 1) << 6;
  int trow = tid >> 3, cb = tid & 7;
  f32x4 acc[4][4] = {};
  for (int kb = 0; kb < 24; ++kb) {
    int i = 2 * sp + kb / 12, dinb = kb % 12;
    #pragma unroll
    for (int s = 0; s < 4; ++s) {
      int row = trow + (s << 5);
      int t = m0 + row;
      u16 pk[8] = {0, 0, 0, 0, 0, 0, 0, 0};
      if (i <= (t & 7)) {
        const float* src = delta + (t - i) * 768 + dinb * 64 + (cb << 3);
        f32x4 v0 = *(const f32x4*)src;
        f32x4 v1 = *(const f32x4*)(src + 4);
        #pragma unroll
        for (int e = 0; e < 4; ++e) { pk[e] = f2b(v0[e]); pk[4 + e] = f2b(v1[e]); }
      }
      *(u32x4*)&As[row * 64 + ((cb ^ (row & 7)) << 3)] = *(u32x4*)pk;
    }
    stage128(Rbig + i * RJ + n0 * 1536 + dinb * 64, 1536, Bs);
    __syncthreads();
    mfma_tile(As, Bs, lane, wm, wn, acc);
    __syncthreads();
  }
  int q = lane >> 4, cn = lane & 15;
  #pragma unroll
  for (int i = 0; i < 4; ++i)
    #pragma unroll
    for (int j = 0; j < 4; ++j)
      #pragma unroll
      for (int r = 0; r < 4; ++r) {
        int m = m0 + wm + i * 16 + q * 4 + r;
        int n = n0 + wn + j * 16 + cn;
        unsafeAtomicAdd(&Hbuf[m * 768 + n], acc[i][j][r]);
      }
}

// warm round A: S[c] = J @ S0[c] + h(8c-9), where S0[c][q] = H[8c-17-(q>=768)][o]
// (A-operand staged from Hbuf on the fly).  J rows: n<768 -> R_8[n], else R_7[n-768].
__global__ __launch_bounds__(256) void k_scan_roundA(const u16* __restrict__ Rbig,
                                                     const float* __restrict__ Hbuf,
                                                     u16* __restrict__ Sout) {
  __shared__ __align__(16) u16 As[128 * 64];
  __shared__ __align__(16) u16 Bs[128 * 64];
  int bid = blockIdx.x;
  int nt = bid % 12, mt = bid / 12;
  int m0 = mt << 7, n0 = nt << 7;
  const u16* Bg = (nt < 6) ? (Rbig + 8 * RJ + n0 * 1536)
                           : (Rbig + 7 * RJ + (n0 - 768) * 1536);
  int tid = threadIdx.x, lane = tid & 63, wave = tid >> 6;
  int wm = (wave & 1) << 6, wn = (wave >> 1) << 6;
  int trow = tid >> 3, cb = tid & 7;
  f32x4 acc[4][4] = {};
  for (int kb = 0; kb < 24; ++kb) {
    #pragma unroll
    for (int s = 0; s < 4; ++s) {
      int row = trow + (s << 5);
      int c = m0 + row;
      int qb = kb * 64 + (cb << 3);
      int side = (qb >= 768) ? 1 : 0;
      int o0 = qb - side * 768;
      int t = 8 * c - 17 - side;
      u16 pk[8] = {0, 0, 0, 0, 0, 0, 0, 0};
      if (t >= 0) {
        const float* src = Hbuf + t * 768 + o0;
        f32x4 v0 = *(const f32x4*)src;
        f32x4 v1 = *(const f32x4*)(src + 4);
        #pragma unroll
        for (int e = 0; e < 4; ++e) { pk[e] = f2b(v0[e]); pk[4 + e] = f2b(v1[e]); }
      }
      *(u32x4*)&As[row * 64 + ((cb ^ (row & 7)) << 3)] = *(u32x4*)pk;
    }
    stage128(Bg + kb * 64, 1536, Bs);
    __syncthreads();
    mfma_tile(As, Bs, lane, wm, wn, acc);
    __syncthreads();
  }
  int q = lane >> 4, cn = lane & 15;
  #pragma unroll
  for (int i = 0; i < 4; ++i)
    #pragma unroll
    for (int j = 0; j < 4; ++j)
      #pragma unroll
      for (int r = 0; r < 4; ++r) {
        int c = m0 + wm + i * 16 + q * 4 + r;
        int n = n0 + wn + j * 16 + cn;
        int side = (n < 768) ? 0 : 1;
        int t = 8 * c - 9 - side;
        int o = n - side * 768;
        float val = acc[i][j][r] + ((t >= 0) ? Hbuf[t * 768 + o] : 0.f);
        Sout[c * 1536 + n] = f2b(val);
      }
}

// warm round B: Snew[c] = J @ Sin[c] + h(8c-1)
__global__ __launch_bounds__(256) void k_scan_round(const u16* __restrict__ Sin,
                                                    const u16* __restrict__ Rbig,
                                                    const float* __restrict__ Hbuf,
                                                    u16* __restrict__ Sout) {
  __shared__ __align__(16) u16 As[128 * 64];
  __shared__ __align__(16) u16 Bs[128 * 64];
  int bid = blockIdx.x;
  int nt = bid % 12, mt = bid / 12;
  int m0 = mt << 7, n0 = nt << 7;
  const u16* Bg = (nt < 6) ? (Rbig + 8 * RJ + n0 * 1536)
                           : (Rbig + 7 * RJ + (n0 - 768) * 1536);
  int tid = threadIdx.x, lane = tid & 63, wave = tid >> 6;
  int wm = (wave & 1) << 6, wn = (wave >> 1) << 6;
  f32x4 acc[4][4] = {};
  for (int kb = 0; kb < 24; ++kb) {
    stage128(Sin + m0 * 1536 + kb * 64, 1536, As);
    stage128(Bg + kb * 64, 1536, Bs);
    __syncthreads();
    mfma_tile(As, Bs, lane, wm, wn, acc);
    __syncthreads();
  }
  int q = lane >> 4, cn = lane & 15;
  #pragma unroll
  for (int i = 0; i < 4; ++i)
    #pragma unroll
    for (int j = 0; j < 4; ++j)
      #pragma unroll
      for (int r = 0; r < 4; ++r) {
        int c = m0 + wm + i * 16 + q * 4 + r;
        int n = n0 + wn + j * 16 + cn;
        int side = (n < 768) ? 0 : 1;
        int t = 8 * c - 1 - side;
        int o = n - side * 768;
        float val = acc[i][j][r] + ((t >= 0) ? Hbuf[t * 768 + o] : 0.f);
        Sout[c * 1536 + n] = f2b(val);
      }
}

// output: y[8c+jj] = (R_{jj+1} @ S[c])[o] + H[8c+jj][o]
__global__ __launch_bounds__(256) void k_scan_out(const u16* __restrict__ Sin,
                                                  const u16* __restrict__ Rbig,
                                                  const float* __restrict__ Hbuf,
                                                  float* __restrict__ out) {
  __shared__ __align__(16) u16 As[128 * 64];
  __shared__ __align__(16) u16 Bs[128 * 64];
  int bid = blockIdx.x;
  int nt = bid % 48, mt = bid / 48;
  int m0 = mt << 7, n0 = nt << 7;
  const u16* Bg = Rbig + RJ + n0 * 1536;   // rows of [R_1; ...; R_8]
  int tid = threadIdx.x, lane = tid & 63, wave = tid >> 6;
  int wm = (wave & 1) << 6, wn = (wave >> 1) << 6;
  f32x4 acc[4][4] = {};
  for (int kb = 0; kb < 24; ++kb) {
    stage128(Sin + m0 * 1536 + kb * 64, 1536, As);
    stage128(Bg + kb * 64, 1536, Bs);
    __syncthreads();
    mfma_tile(As, Bs, lane, wm, wn, acc);
    __syncthreads();
  }
  int q = lane >> 4, cn = lane & 15;
  #pragma unroll
  for (int i = 0; i < 4; ++i)
    #pragma unroll
    for (int j = 0; j < 4; ++j)
      #pragma unroll
      for (int r = 0; r < 4; ++r) {
        int c = m0 + wm + i * 16 + q * 4 + r;
        int n = n0 + wn + j * 16 + cn;
        int jj = n / 768, o = n % 768;
        int t = 8 * c + jj;
        out[t * 768 + o] = acc[i][j][r] + Hbuf[t * 768 + o];
      }
}

// ---------------------------------------------------------------------------
extern "C" void kernel_launch(void* const* d_in, const int* in_sizes, int n_in,
                              void* d_out, int out_size, void* d_ws, size_t ws_size,
                              hipStream_t stream) {
  const float* u    = (const float*)d_in[0];
  const float* my   = (const float*)d_in[1];
  const float* mu   = (const float*)d_in[2];
  const float* mphi = (const float*)d_in[3];
  const float* ev   = (const float*)d_in[4];
  const float* evec = (const float*)d_in[5];
  float* out = (float*)d_out;
  char* ws = (char*)d_ws;

  u16*   ub    = (u16*)(ws + WS_UB);
  u16*   mphiT = (u16*)(ws + WS_MPHIT);
  u16*   b2t   = (u16*)(ws + WS_B2T);
  u16*   tt    = (u16*)(ws + WS_TT);
  u16*   zt    = (u16*)(ws + WS_ZT);
  float* delta = (float*)(ws + WS_DELTA);
  u16*   Rbig  = (u16*)(ws + OV_RBIG);
  u16*   Ct0   = (u16*)(ws + OV_CT0);
  u16*   Ct1   = (u16*)(ws + OV_CT1);
  u16*   Ct2   = (u16*)(ws + OV_CT2);
  float* Hbuf  = (float*)(ws + OV_HBUF);
  u16*   SA    = (u16*)(ws + OV_SBUF);
  u16*   SB    = SA + 256 * 1536;

  hipLaunchKernelGGL(k_prep, dim3(59142), dim3(256), 0, stream,
                     u, mphi, ev, mu, evec, delta, ub, mphiT, b2t, tt);
  hipLaunchKernelGGL(k_gemm_zt,    dim3(1152), dim3(256), 0, stream,
                     mphiT, ub + 2 * 768, zt);
  hipLaunchKernelGGL(k_gemm_delta, dim3(432),  dim3(256), 0, stream,
                     tt, zt, ub, b2t, delta);

  // --- scan prep (overlays zt; stream-ordered after k_gemm_delta) ---
  hipLaunchKernelGGL(k_chain_init, dim3(24576), dim3(256), 0, stream,
                     my, Rbig, Ct0, Ct1, Hbuf);
  hipLaunchKernelGGL(k_gemm_R, dim3(72),  dim3(256), 0, stream,
                     Rbig + RJ, Ct0, Rbig + 2 * RJ, Ct1, 1);            // R_2
  hipLaunchKernelGGL(k_gemm_R, dim3(144), dim3(256), 0, stream,
                     Rbig + RJ, Ct1, Rbig + 3 * RJ, Ct2, 2);            // R_3,R_4
  hipLaunchKernelGGL(k_gemm_R, dim3(288), dim3(256), 0, stream,
                     Rbig + RJ, Ct2, Rbig + 5 * RJ, (u16*)nullptr, 0);  // R_5..R_8

  hipLaunchKernelGGL(k_conv, dim3(384), dim3(256), 0, stream, delta, Rbig, Hbuf);

  // --- scan: 2 warm-up jumps (A of round 1 staged from Hbuf) + output ---
  hipLaunchKernelGGL(k_scan_roundA, dim3(24), dim3(256), 0, stream, Rbig, Hbuf, SA);
  hipLaunchKernelGGL(k_scan_round,  dim3(24), dim3(256), 0, stream, SA, Rbig, Hbuf, SB);
  hipLaunchKernelGGL(k_scan_out,    dim3(96), dim3(256), 0, stream, SB, Rbig, Hbuf, out);
}

// Round 20
// 621.750 us; speedup vs baseline: 1.2512x; 1.0004x over previous
//
#include <hip/hip_runtime.h>
#include <hip/hip_bf16.h>
#include <stdint.h>

// STU forward: y = scan(m_y, (x_tilde @ m_phi) + AR(m_u, u))
// R5: 256x128 MFMA tiles for the two big GEMMs (32 MFMA per barrier-slab).
// R6: XCD-chunked blockIdx swizzle (T1) on k_gemm_zt / k_gemm_delta / k_conv.
// R11: FINAL: verified 622.0 us (Round 18; matches R2's 623.7). Ledger:
//   R7  s-major enum:   FETCH 188->84 MB but dur +4% (not BW-bound).
//   R8  dbuf pipeline:  -74% (96KB LDS -> 1 blk/CU; drain-0 prefetch null).
//   R10 kk-split 2-way: occupancy unmoved; atomic epilogue doubled (+27us).
// Next-session lever: 8-phase counted-vmcnt rewrite, k_gemm_zt first.

typedef unsigned short u16;
typedef unsigned int   u32;
typedef __bf16  bf16x8 __attribute__((ext_vector_type(8)));
typedef float   f32x4  __attribute__((ext_vector_type(4)));
typedef u32     u32x4  __attribute__((ext_vector_type(4)));

#define MFMA(a,b,c) __builtin_amdgcn_mfma_f32_16x16x32_bf16(a,b,c,0,0,0)
#define RJ 1179648   // elems per R_j (768*1536)

__device__ __forceinline__ u16 f2b(float f) {           // fp32 -> bf16 bits, RNE
  union { float f; u32 u; } v; v.f = f;
  return (u16)((v.u + 0x7fffu + ((v.u >> 16) & 1u)) >> 16);
}

__device__ __forceinline__ void gld16(const u16* g, u16* l) {
  __builtin_amdgcn_global_load_lds(
      (const __attribute__((address_space(1))) u32*)g,
      (__attribute__((address_space(3))) u32*)l, 16, 0, 0);
}

// ---------------- workspace layout (bytes) ----------------
#define WS_UB     0            // [2050][768] bf16
#define WS_MPHIT  3148800      // [18432][768] bf16
#define WS_B2T    31460352     // [3][768][768] bf16
#define WS_TT     34999296     // [17][24][128][128] bf16 (slot 0 = delta-tile for dlt=-1, all zero)
#define WS_ZT     48368640     // [24][768][2048] bf16 (dead after k_gemm_delta)
#define WS_DELTA  123866112    // [2048][768] f32  (end 130157568)
// overlays inside zt region (phase 2, after k_gemm_delta):
#define OV_RBIG   (WS_ZT + 0)          // [9][768][1536] bf16
#define OV_CT0    (WS_ZT + 21233664)   // [1536][1536] bf16
#define OV_CT1    (WS_ZT + 25952256)
#define OV_CT2    (WS_ZT + 30670848)
#define OV_HBUF   (WS_ZT + 35389440)   // [2048][768] f32
#define OV_SBUF   (WS_ZT + 41680896)   // [2][256][1536] bf16

// ---------------------------------------------------------------------------
// k_prep: zero delta | repack u | repack mphi | repack mu | make_T  (one launch)
__global__ void k_prep(const float* __restrict__ u, const float* __restrict__ mphi,
                       const float* __restrict__ ev, const float* __restrict__ mu,
                       const float* __restrict__ evec,
                       float* __restrict__ delta, u16* __restrict__ ub,
                       u16* __restrict__ mphiT, u16* __restrict__ b2t,
                       u16* __restrict__ tt) {
  __shared__ float tile[32][33];
  int b = blockIdx.x, tid = threadIdx.x;
  if (b < 6144) {                       // zero delta
    delta[b * 256 + tid] = 0.f;
  } else if (b < 12294) {               // repack u (+2 guard rows)
    int i = (b - 6144) * 256 + tid;
    ub[i] = (i < 2 * 768) ? (u16)0 : f2b(u[i - 2 * 768]);
  } else if (b < 26118) {               // repack mphi (transpose per k, scale)
    int bid = b - 12294;
    int k = bid / 576, rem = bid % 576;
    int ti = rem / 24, tj = rem % 24;
    int c = tid & 31, r0 = tid >> 5;
    float s = powf(ev[k], 0.25f);
    #pragma unroll
    for (int rr = 0; rr < 4; ++rr) {
      int r = r0 + (rr << 3);
      tile[r][c] = mphi[(k * 768 + ti * 32 + r) * 768 + tj * 32 + c];
    }
    __syncthreads();
    #pragma unroll
    for (int rr = 0; rr < 4; ++rr) {
      int r = r0 + (rr << 3);
      mphiT[(k * 768 + tj * 32 + r) * 768 + ti * 32 + c] = f2b(tile[c][r] * s);
    }
  } else if (b < 33030) {               // repack mu
    int i = (b - 26118) * 256 + tid;
    int kk = i / (768 * 768);
    int rem = i % (768 * 768);
    int o = rem / 768, ii = rem % 768;
    b2t[i] = f2b(mu[(o * 768 + ii) * 3 + kk]);
  } else {                              // make_T (17 slots; slot 0 auto-zero)
    int i = (b - 33030) * 256 + tid;
    int c = i & 127, r = (i >> 7) & 127;
    int kk = (i >> 14) % 24, sl = (i >> 14) / 24;
    int t = (sl - 1) * 128 + r - c - 2;
    tt[i] = (t >= 0 && t < 2048) ? f2b(evec[t * 24 + kk]) : (u16)0;
  }
}

// ---------------------------------------------------------------------------
// Stage 128 rows x 64 u16 (16 KB) via async global_load_lds, XOR-swizzled:
// LDS slot (row, cb) holds global (row, cb ^ (row&7)).
__device__ __forceinline__ void stage128(const u16* __restrict__ g, int ld,
                                         u16* __restrict__ lds) {
  int tid = threadIdx.x;
  int r0 = tid >> 3, cb = tid & 7, wave = tid >> 6;
  #pragma unroll
  for (int s = 0; s < 4; ++s) {
    int row = r0 + (s << 5);
    int cbx = (cb ^ (row & 7)) << 3;
    gld16(g + row * ld + cbx, lds + (s << 11) + (wave << 9));
  }
}

// 128x128 tile MFMA over one K=64 slab (swizzle-aware reads).
__device__ __forceinline__ void mfma_tile(const u16* As, const u16* Bs, int lane,
                                          int wm, int wn, f32x4 acc[4][4]) {
  int cn = lane & 15, q = lane >> 4;
  #pragma unroll
  for (int ks = 0; ks < 2; ++ks) {
    int blk = ks * 4 + q;
    bf16x8 af[4], bg[4];
    #pragma unroll
    for (int i = 0; i < 4; ++i) {
      int row = wm + i * 16 + cn;
      af[i] = *(const bf16x8*)&As[row * 64 + ((blk ^ (row & 7)) << 3)];
    }
    #pragma unroll
    for (int j = 0; j < 4; ++j) {
      int row = wn + j * 16 + cn;
      bg[j] = *(const bf16x8*)&Bs[row * 64 + ((blk ^ (row & 7)) << 3)];
    }
    #pragma unroll
    for (int i = 0; i < 4; ++i)
      #pragma unroll
      for (int j = 0; j < 4; ++j)
        acc[i][j] = MFMA(af[i], bg[j], acc[i][j]);
  }
}

// 256x128 tile: wave owns 64 M-rows (wm = wave*64), all 128 N-cols. 32 MFMA/slab.
__device__ __forceinline__ void mfma_tile256(const u16* As, const u16* Bs, int lane,
                                             int wm, f32x4 acc[4][8]) {
  int cn = lane & 15, q = lane >> 4;
  #pragma unroll
  for (int ks = 0; ks < 2; ++ks) {
    int blk = ks * 4 + q;
    bf16x8 af[4], bg[8];
    #pragma unroll
    for (int i = 0; i < 4; ++i) {
      int row = wm + i * 16 + cn;
      af[i] = *(const bf16x8*)&As[row * 64 + ((blk ^ (row & 7)) << 3)];
    }
    #pragma unroll
    for (int j = 0; j < 8; ++j) {
      int row = j * 16 + cn;
      bg[j] = *(const bf16x8*)&Bs[row * 64 + ((blk ^ (row & 7)) << 3)];
    }
    #pragma unroll
    for (int i = 0; i < 4; ++i)
      #pragma unroll
      for (int j = 0; j < 8; ++j)
        acc[i][j] = MFMA(af[i], bg[j], acc[i][j]);
  }
}

// K2: Zt[18432 x 2048] = mphiT @ ub^T.  256x128 tiles, grid 72x16.
__global__ __launch_bounds__(256, 2) void k_gemm_zt(const u16* __restrict__ A,
                                                    const u16* __restrict__ B,
                                                    u16* __restrict__ C) {
  __shared__ __align__(16) u16 As[256 * 64];
  __shared__ __align__(16) u16 Bs[128 * 64];
  int bid = blockIdx.x;
  bid = (bid & 7) * 144 + (bid >> 3);   // XCD chunk swizzle (1152/8 = 144)
  int nt = bid & 15, mt = bid >> 4;
  int m0 = mt << 8, n0 = nt << 7;
  int tid = threadIdx.x, lane = tid & 63, wave = tid >> 6;
  int wm = wave << 6;
  f32x4 acc[4][8] = {};
  for (int kb = 0; kb < 12; ++kb) {
    stage128(A + m0 * 768 + kb * 64, 768, As);
    stage128(A + (m0 + 128) * 768 + kb * 64, 768, As + 8192);
    stage128(B + n0 * 768 + kb * 64, 768, Bs);
    __syncthreads();
    mfma_tile256(As, Bs, lane, wm, acc);
    __syncthreads();
  }
  int q = lane >> 4, cn = lane & 15;
  #pragma unroll
  for (int i = 0; i < 4; ++i)
    #pragma unroll
    for (int j = 0; j < 8; ++j)
      #pragma unroll
      for (int r = 0; r < 4; ++r) {
        int m = m0 + wm + i * 16 + q * 4 + r;
        int n = n0 + j * 16 + cn;
        C[m * 2048 + n] = f2b(acc[i][j][r]);
      }
}

// K3: delta = sum_k T_k @ Zt[k] + AR.  256x128 tiles; block = (db, a, s).
// Rows 0-127 of the A tile use dlt = 2a-s (slot dlt+1; slot 0 is all-zero),
// rows 128-255 use dlt = 2a+1-s.
__global__ __launch_bounds__(256, 2) void k_gemm_delta(const u16* __restrict__ tt,
                                                       const u16* __restrict__ zt,
                                                       const u16* __restrict__ ub,
                                                       const u16* __restrict__ b2t,
                                                       float* __restrict__ delta) {
  __shared__ __align__(16) u16 As[256 * 64];
  __shared__ __align__(16) u16 Bs[128 * 64];
  int bid = blockIdx.x;
  bid = (bid % 8) * 54 + bid / 8;       // XCD chunk swizzle (432/8 = 54)
  int db = bid % 6;
  int r2 = bid / 6;                 // [0,72) -> (a, s), s in [0, 2a+2)
  int a = 0, s = 0;
  for (;; ++a) { int cnt = 2 * a + 2; if (r2 < cnt) { s = r2; break; } r2 -= cnt; }
  int n0 = db << 7;
  int tid = threadIdx.x, lane = tid & 63, wave = tid >> 6;
  int wm = wave << 6;
  f32x4 acc[4][8] = {};
  int d1 = 2 * a + 1 - s;                         // slot for lower half = d1+1
  const u16* A0 = tt + (size_t)d1 * 24 * 16384;         // slot d1 (= dlt0+1)
  const u16* A1 = tt + (size_t)(d1 + 1) * 24 * 16384;   // slot d1+1
  for (int kk = 0; kk < 24; ++kk) {
    const u16* Bg = zt + kk * (768 * 2048) + n0 * 2048 + s * 128;
    #pragma unroll
    for (int hf = 0; hf < 2; ++hf) {
      stage128(A0 + kk * 16384 + hf * 64, 128, As);
      stage128(A1 + kk * 16384 + hf * 64, 128, As + 8192);
      stage128(Bg + hf * 64, 2048, Bs);
      __syncthreads();
      mfma_tile256(As, Bs, lane, wm, acc);
      __syncthreads();
    }
  }
  // AR taps: tap kku owned by s == min(kku, 2a+1)
  #pragma unroll
  for (int kku = 0; kku < 3; ++kku) {
    int owner = (kku <= 2 * a + 1) ? kku : 2 * a + 1;
    if (s != owner) continue;
    const u16* Au = ub + (2 + a * 256 - kku) * 768;
    const u16* Bg = b2t + kku * (768 * 768) + n0 * 768;
    for (int ic = 0; ic < 12; ++ic) {
      stage128(Au + ic * 64, 768, As);
      stage128(Au + 128 * 768 + ic * 64, 768, As + 8192);
      stage128(Bg + ic * 64, 768, Bs);
      __syncthreads();
      mfma_tile256(As, Bs, lane, wm, acc);
      __syncthreads();
    }
  }
  int q = lane >> 4, cn = lane & 15;
  #pragma unroll
  for (int i = 0; i < 4; ++i)
    #pragma unroll
    for (int j = 0; j < 8; ++j)
      #pragma unroll
      for (int r = 0; r < 4; ++r) {
        int m = a * 256 + wm + i * 16 + q * 4 + r;
        int n = n0 + j * 16 + cn;
        unsafeAtomicAdd(&delta[m * 768 + n], acc[i][j][r]);
      }
}

// ---------------------------------------------------------------------------
// chain init: R_0=[I|0], R_1=[A1|A2], Ct0=[R_1;R_0]^T, Ct1 right half=R_1^T, zero H.
__global__ void k_chain_init(const float* __restrict__ my, u16* __restrict__ Rbig,
                             u16* __restrict__ Ct0, u16* __restrict__ Ct1,
                             float* __restrict__ Hbuf) {
  int b = blockIdx.x, tid = threadIdx.x;
  if (b < 4608) {                       // R_0, R_1
    int i = b * 256 + tid;
    int o = i / 1536, q = i % 1536;
    Rbig[i] = (q == o) ? (u16)0x3F80 : (u16)0;
    Rbig[RJ + i] = f2b(my[i]);
  } else if (b < 13824) {               // Ct0[n][p]
    int i = (b - 4608) * 256 + tid;
    int n = i / 1536, p = i % 1536;
    u16 v;
    if (p < 768) v = f2b(my[p * 1536 + n]);
    else         v = (p - 768 == n) ? (u16)0x3F80 : (u16)0;
    Ct0[i] = v;
  } else if (b < 18432) {               // Ct1[n][768+i] = R_1[i][n]
    int i = (b - 13824) * 256 + tid;
    int n = i / 768, ii = i % 768;
    Ct1[n * 1536 + 768 + ii] = f2b(my[ii * 1536 + n]);
  } else {                              // zero Hbuf
    int i = (b - 18432) * 256 + tid;
    Hbuf[i] = 0.f;
  }
}

// M x 1536 x 1536 GEMM (B = Ct, [n][k] layout). Dual epilogue: row-major out +
// optional transposed write into the next doubling's Ct.
// mode 0: none; 1: tcol=m (R_2^T -> left); 2: m<768 -> 768+m (R_3^T right),
// m>=768 -> m-768 (R_4^T left).
__global__ __launch_bounds__(256) void k_gemm_R(const u16* __restrict__ A,
                                                const u16* __restrict__ Ct,
                                                u16* __restrict__ Co,
                                                u16* __restrict__ CtT, int mode) {
  __shared__ __align__(16) u16 As[128 * 64];
  __shared__ __align__(16) u16 Bs[128 * 64];
  int bid = blockIdx.x;
  int nt = bid % 12, mt = bid / 12;
  int m0 = mt << 7, n0 = nt << 7;
  int tid = threadIdx.x, lane = tid & 63, wave = tid >> 6;
  int wm = (wave & 1) << 6, wn = (wave >> 1) << 6;
  f32x4 acc[4][4] = {};
  for (int kb = 0; kb < 24; ++kb) {
    stage128(A + m0 * 1536 + kb * 64, 1536, As);
    stage128(Ct + n0 * 1536 + kb * 64, 1536, Bs);
    __syncthreads();
    mfma_tile(As, Bs, lane, wm, wn, acc);
    __syncthreads();
  }
  int q = lane >> 4, cn = lane & 15;
  #pragma unroll
  for (int i = 0; i < 4; ++i)
    #pragma unroll
    for (int j = 0; j < 4; ++j) {
      int n = n0 + wn + j * 16 + cn;
      int mb = m0 + wm + i * 16 + q * 4;
      u16 pk[4];
      #pragma unroll
      for (int r = 0; r < 4; ++r) {
        u16 v = f2b(acc[i][j][r]);
        Co[(mb + r) * 1536 + n] = v;
        pk[r] = v;
      }
      if (mode) {
        int tcol = (mode == 1) ? mb : ((mb < 768) ? 768 + mb : mb - 768);
        *(uint2*)&CtT[n * 1536 + tcol] = *(uint2*)pk;
      }
    }
}

// H[t][o] = sum_{i<=t&7} U_i[o][:] . delta[t-i][:]  (delta read f32, cast on the fly)
__global__ __launch_bounds__(256) void k_conv(const float* __restrict__ delta,
                                              const u16* __restrict__ Rbig,
                                              float* __restrict__ Hbuf) {
  __shared__ __align__(16) u16 As[128 * 64];
  __shared__ __align__(16) u16 Bs[128 * 64];
  int bid = blockIdx.x;
  bid = (bid & 7) * 48 + (bid >> 3);    // XCD chunk swizzle (384/8 = 48)
  int nt = bid % 6, mt = (bid / 6) % 16, sp = bid / 96;
  int m0 = mt << 7, n0 = nt << 7;
  int tid = threadIdx.x, lane = tid & 63, wave = tid >> 6;
  int wm = (wave & 1) << 6, wn = (wave >> 1) << 6;
  int trow = tid >> 3, cb = tid & 7;
  f32x4 acc[4][4] = {};
  for (int kb = 0; kb < 24; ++kb) {
    int i = 2 * sp + kb / 12, dinb = kb % 12;
    #pragma unroll
    for (int s = 0; s < 4; ++s) {
      int row = trow + (s << 5);
      int t = m0 + row;
      u16 pk[8] = {0, 0, 0, 0, 0, 0, 0, 0};
      if (i <= (t & 7)) {
        const float* src = delta + (t - i) * 768 + dinb * 64 + (cb << 3);
        f32x4 v0 = *(const f32x4*)src;
        f32x4 v1 = *(const f32x4*)(src + 4);
        #pragma unroll
        for (int e = 0; e < 4; ++e) { pk[e] = f2b(v0[e]); pk[4 + e] = f2b(v1[e]); }
      }
      *(u32x4*)&As[row * 64 + ((cb ^ (row & 7)) << 3)] = *(u32x4*)pk;
    }
    stage128(Rbig + i * RJ + n0 * 1536 + dinb * 64, 1536, Bs);
    __syncthreads();
    mfma_tile(As, Bs, lane, wm, wn, acc);
    __syncthreads();
  }
  int q = lane >> 4, cn = lane & 15;
  #pragma unroll
  for (int i = 0; i < 4; ++i)
    #pragma unroll
    for (int j = 0; j < 4; ++j)
      #pragma unroll
      for (int r = 0; r < 4; ++r) {
        int m = m0 + wm + i * 16 + q * 4 + r;
        int n = n0 + wn + j * 16 + cn;
        unsafeAtomicAdd(&Hbuf[m * 768 + n], acc[i][j][r]);
      }
}

// warm round A: S[c] = J @ S0[c] + h(8c-9), where S0[c][q] = H[8c-17-(q>=768)][o]
// (A-operand staged from Hbuf on the fly).  J rows: n<768 -> R_8[n], else R_7[n-768].
__global__ __launch_bounds__(256) void k_scan_roundA(const u16* __restrict__ Rbig,
                                                     const float* __restrict__ Hbuf,
                                                     u16* __restrict__ Sout) {
  __shared__ __align__(16) u16 As[128 * 64];
  __shared__ __align__(16) u16 Bs[128 * 64];
  int bid = blockIdx.x;
  int nt = bid % 12, mt = bid / 12;
  int m0 = mt << 7, n0 = nt << 7;
  const u16* Bg = (nt < 6) ? (Rbig + 8 * RJ + n0 * 1536)
                           : (Rbig + 7 * RJ + (n0 - 768) * 1536);
  int tid = threadIdx.x, lane = tid & 63, wave = tid >> 6;
  int wm = (wave & 1) << 6, wn = (wave >> 1) << 6;
  int trow = tid >> 3, cb = tid & 7;
  f32x4 acc[4][4] = {};
  for (int kb = 0; kb < 24; ++kb) {
    #pragma unroll
    for (int s = 0; s < 4; ++s) {
      int row = trow + (s << 5);
      int c = m0 + row;
      int qb = kb * 64 + (cb << 3);
      int side = (qb >= 768) ? 1 : 0;
      int o0 = qb - side * 768;
      int t = 8 * c - 17 - side;
      u16 pk[8] = {0, 0, 0, 0, 0, 0, 0, 0};
      if (t >= 0) {
        const float* src = Hbuf + t * 768 + o0;
        f32x4 v0 = *(const f32x4*)src;
        f32x4 v1 = *(const f32x4*)(src + 4);
        #pragma unroll
        for (int e = 0; e < 4; ++e) { pk[e] = f2b(v0[e]); pk[4 + e] = f2b(v1[e]); }
      }
      *(u32x4*)&As[row * 64 + ((cb ^ (row & 7)) << 3)] = *(u32x4*)pk;
    }
    stage128(Bg + kb * 64, 1536, Bs);
    __syncthreads();
    mfma_tile(As, Bs, lane, wm, wn, acc);
    __syncthreads();
  }
  int q = lane >> 4, cn = lane & 15;
  #pragma unroll
  for (int i = 0; i < 4; ++i)
    #pragma unroll
    for (int j = 0; j < 4; ++j)
      #pragma unroll
      for (int r = 0; r < 4; ++r) {
        int c = m0 + wm + i * 16 + q * 4 + r;
        int n = n0 + wn + j * 16 + cn;
        int side = (n < 768) ? 0 : 1;
        int t = 8 * c - 9 - side;
        int o = n - side * 768;
        float val = acc[i][j][r] + ((t >= 0) ? Hbuf[t * 768 + o] : 0.f);
        Sout[c * 1536 + n] = f2b(val);
      }
}

// warm round B: Snew[c] = J @ Sin[c] + h(8c-1)
__global__ __launch_bounds__(256) void k_scan_round(const u16* __restrict__ Sin,
                                                    const u16* __restrict__ Rbig,
                                                    const float* __restrict__ Hbuf,
                                                    u16* __restrict__ Sout) {
  __shared__ __align__(16) u16 As[128 * 64];
  __shared__ __align__(16) u16 Bs[128 * 64];
  int bid = blockIdx.x;
  int nt = bid % 12, mt = bid / 12;
  int m0 = mt << 7, n0 = nt << 7;
  const u16* Bg = (nt < 6) ? (Rbig + 8 * RJ + n0 * 1536)
                           : (Rbig + 7 * RJ + (n0 - 768) * 1536);
  int tid = threadIdx.x, lane = tid & 63, wave = tid >> 6;
  int wm = (wave & 1) << 6, wn = (wave >> 1) << 6;
  f32x4 acc[4][4] = {};
  for (int kb = 0; kb < 24; ++kb) {
    stage128(Sin + m0 * 1536 + kb * 64, 1536, As);
    stage128(Bg + kb * 64, 1536, Bs);
    __syncthreads();
    mfma_tile(As, Bs, lane, wm, wn, acc);
    __syncthreads();
  }
  int q = lane >> 4, cn = lane & 15;
  #pragma unroll
  for (int i = 0; i < 4; ++i)
    #pragma unroll
    for (int j = 0; j < 4; ++j)
      #pragma unroll
      for (int r = 0; r < 4; ++r) {
        int c = m0 + wm + i * 16 + q * 4 + r;
        int n = n0 + wn + j * 16 + cn;
        int side = (n < 768) ? 0 : 1;
        int t = 8 * c - 1 - side;
        int o = n - side * 768;
        float val = acc[i][j][r] + ((t >= 0) ? Hbuf[t * 768 + o] : 0.f);
        Sout[c * 1536 + n] = f2b(val);
      }
}

// output: y[8c+jj] = (R_{jj+1} @ S[c])[o] + H[8c+jj][o]
__global__ __launch_bounds__(256) void k_scan_out(const u16* __restrict__ Sin,
                                                  const u16* __restrict__ Rbig,
                                                  const float* __restrict__ Hbuf,
                                                  float* __restrict__ out) {
  __shared__ __align__(16) u16 As[128 * 64];
  __shared__ __align__(16) u16 Bs[128 * 64];
  int bid = blockIdx.x;
  int nt = bid % 48, mt = bid / 48;
  int m0 = mt << 7, n0 = nt << 7;
  const u16* Bg = Rbig + RJ + n0 * 1536;   // rows of [R_1; ...; R_8]
  int tid = threadIdx.x, lane = tid & 63, wave = tid >> 6;
  int wm = (wave & 1) << 6, wn = (wave >> 1) << 6;
  f32x4 acc[4][4] = {};
  for (int kb = 0; kb < 24; ++kb) {
    stage128(Sin + m0 * 1536 + kb * 64, 1536, As);
    stage128(Bg + kb * 64, 1536, Bs);
    __syncthreads();
    mfma_tile(As, Bs, lane, wm, wn, acc);
    __syncthreads();
  }
  int q = lane >> 4, cn = lane & 15;
  #pragma unroll
  for (int i = 0; i < 4; ++i)
    #pragma unroll
    for (int j = 0; j < 4; ++j)
      #pragma unroll
      for (int r = 0; r < 4; ++r) {
        int c = m0 + wm + i * 16 + q * 4 + r;
        int n = n0 + wn + j * 16 + cn;
        int jj = n / 768, o = n % 768;
        int t = 8 * c + jj;
        out[t * 768 + o] = acc[i][j][r] + Hbuf[t * 768 + o];
      }
}

// ---------------------------------------------------------------------------
extern "C" void kernel_launch(void* const* d_in, const int* in_sizes, int n_in,
                              void* d_out, int out_size, void* d_ws, size_t ws_size,
                              hipStream_t stream) {
  const float* u    = (const float*)d_in[0];
  const float* my   = (const float*)d_in[1];
  const float* mu   = (const float*)d_in[2];
  const float* mphi = (const float*)d_in[3];
  const float* ev   = (const float*)d_in[4];
  const float* evec = (const float*)d_in[5];
  float* out = (float*)d_out;
  char* ws = (char*)d_ws;

  u16*   ub    = (u16*)(ws + WS_UB);
  u16*   mphiT = (u16*)(ws + WS_MPHIT);
  u16*   b2t   = (u16*)(ws + WS_B2T);
  u16*   tt    = (u16*)(ws + WS_TT);
  u16*   zt    = (u16*)(ws + WS_ZT);
  float* delta = (float*)(ws + WS_DELTA);
  u16*   Rbig  = (u16*)(ws + OV_RBIG);
  u16*   Ct0   = (u16*)(ws + OV_CT0);
  u16*   Ct1   = (u16*)(ws + OV_CT1);
  u16*   Ct2   = (u16*)(ws + OV_CT2);
  float* Hbuf  = (float*)(ws + OV_HBUF);
  u16*   SA    = (u16*)(ws + OV_SBUF);
  u16*   SB    = SA + 256 * 1536;

  hipLaunchKernelGGL(k_prep, dim3(59142), dim3(256), 0, stream,
                     u, mphi, ev, mu, evec, delta, ub, mphiT, b2t, tt);
  hipLaunchKernelGGL(k_gemm_zt,    dim3(1152), dim3(256), 0, stream,
                     mphiT, ub + 2 * 768, zt);
  hipLaunchKernelGGL(k_gemm_delta, dim3(432),  dim3(256), 0, stream,
                     tt, zt, ub, b2t, delta);

  // --- scan prep (overlays zt; stream-ordered after k_gemm_delta) ---
  hipLaunchKernelGGL(k_chain_init, dim3(24576), dim3(256), 0, stream,
                     my, Rbig, Ct0, Ct1, Hbuf);
  hipLaunchKernelGGL(k_gemm_R, dim3(72),  dim3(256), 0, stream,
                     Rbig + RJ, Ct0, Rbig + 2 * RJ, Ct1, 1);            // R_2
  hipLaunchKernelGGL(k_gemm_R, dim3(144), dim3(256), 0, stream,
                     Rbig + RJ, Ct1, Rbig + 3 * RJ, Ct2, 2);            // R_3,R_4
  hipLaunchKernelGGL(k_gemm_R, dim3(288), dim3(256), 0, stream,
                     Rbig + RJ, Ct2, Rbig + 5 * RJ, (u16*)nullptr, 0);  // R_5..R_8

  hipLaunchKernelGGL(k_conv, dim3(384), dim3(256), 0, stream, delta, Rbig, Hbuf);

  // --- scan: 2 warm-up jumps (A of round 1 staged from Hbuf) + output ---
  hipLaunchKernelGGL(k_scan_roundA, dim3(24), dim3(256), 0, stream, Rbig, Hbuf, SA);
  hipLaunchKernelGGL(k_scan_round,  dim3(24), dim3(256), 0, stream, SA, Rbig, Hbuf, SB);
  hipLaunchKernelGGL(k_scan_out,    dim3(96), dim3(256), 0, stream, SB, Rbig, Hbuf, out);
}

// Round 21
// 619.468 us; speedup vs baseline: 1.2558x; 1.0037x over previous
//
#include <hip/hip_runtime.h>
#include <hip/hip_bf16.h>
#include <stdint.h>

// STU forward: y = scan(m_y, (x_tilde @ m_phi) + AR(m_u, u))
// R5: 256x128 MFMA tiles for the two big GEMMs (32 MFMA per barrier-slab).
// R6: XCD-chunked blockIdx swizzle (T1) on k_gemm_zt / k_gemm_delta / k_conv.
// R11: FINAL: verified 621.75-623.7 us across three runs (R2/R18/R20). Ledger:
//   R7  s-major enum:   FETCH 188->84 MB but dur +4% (not BW-bound).
//   R8  dbuf pipeline:  -74% (96KB LDS -> 1 blk/CU; drain-0 prefetch null).
//   R10 kk-split 2-way: occupancy unmoved; atomic epilogue doubled (+27us).
// Next-session lever: 8-phase counted-vmcnt rewrite, k_gemm_zt first.

typedef unsigned short u16;
typedef unsigned int   u32;
typedef __bf16  bf16x8 __attribute__((ext_vector_type(8)));
typedef float   f32x4  __attribute__((ext_vector_type(4)));
typedef u32     u32x4  __attribute__((ext_vector_type(4)));

#define MFMA(a,b,c) __builtin_amdgcn_mfma_f32_16x16x32_bf16(a,b,c,0,0,0)
#define RJ 1179648   // elems per R_j (768*1536)

__device__ __forceinline__ u16 f2b(float f) {           // fp32 -> bf16 bits, RNE
  union { float f; u32 u; } v; v.f = f;
  return (u16)((v.u + 0x7fffu + ((v.u >> 16) & 1u)) >> 16);
}

__device__ __forceinline__ void gld16(const u16* g, u16* l) {
  __builtin_amdgcn_global_load_lds(
      (const __attribute__((address_space(1))) u32*)g,
      (__attribute__((address_space(3))) u32*)l, 16, 0, 0);
}

// ---------------- workspace layout (bytes) ----------------
#define WS_UB     0            // [2050][768] bf16
#define WS_MPHIT  3148800      // [18432][768] bf16
#define WS_B2T    31460352     // [3][768][768] bf16
#define WS_TT     34999296     // [17][24][128][128] bf16 (slot 0 = delta-tile for dlt=-1, all zero)
#define WS_ZT     48368640     // [24][768][2048] bf16 (dead after k_gemm_delta)
#define WS_DELTA  123866112    // [2048][768] f32  (end 130157568)
// overlays inside zt region (phase 2, after k_gemm_delta):
#define OV_RBIG   (WS_ZT + 0)          // [9][768][1536] bf16
#define OV_CT0    (WS_ZT + 21233664)   // [1536][1536] bf16
#define OV_CT1    (WS_ZT + 25952256)
#define OV_CT2    (WS_ZT + 30670848)
#define OV_HBUF   (WS_ZT + 35389440)   // [2048][768] f32
#define OV_SBUF   (WS_ZT + 41680896)   // [2][256][1536] bf16

// ---------------------------------------------------------------------------
// k_prep: zero delta | repack u | repack mphi | repack mu | make_T  (one launch)
__global__ void k_prep(const float* __restrict__ u, const float* __restrict__ mphi,
                       const float* __restrict__ ev, const float* __restrict__ mu,
                       const float* __restrict__ evec,
                       float* __restrict__ delta, u16* __restrict__ ub,
                       u16* __restrict__ mphiT, u16* __restrict__ b2t,
                       u16* __restrict__ tt) {
  __shared__ float tile[32][33];
  int b = blockIdx.x, tid = threadIdx.x;
  if (b < 6144) {                       // zero delta
    delta[b * 256 + tid] = 0.f;
  } else if (b < 12294) {               // repack u (+2 guard rows)
    int i = (b - 6144) * 256 + tid;
    ub[i] = (i < 2 * 768) ? (u16)0 : f2b(u[i - 2 * 768]);
  } else if (b < 26118) {               // repack mphi (transpose per k, scale)
    int bid = b - 12294;
    int k = bid / 576, rem = bid % 576;
    int ti = rem / 24, tj = rem % 24;
    int c = tid & 31, r0 = tid >> 5;
    float s = powf(ev[k], 0.25f);
    #pragma unroll
    for (int rr = 0; rr < 4; ++rr) {
      int r = r0 + (rr << 3);
      tile[r][c] = mphi[(k * 768 + ti * 32 + r) * 768 + tj * 32 + c];
    }
    __syncthreads();
    #pragma unroll
    for (int rr = 0; rr < 4; ++rr) {
      int r = r0 + (rr << 3);
      mphiT[(k * 768 + tj * 32 + r) * 768 + ti * 32 + c] = f2b(tile[c][r] * s);
    }
  } else if (b < 33030) {               // repack mu
    int i = (b - 26118) * 256 + tid;
    int kk = i / (768 * 768);
    int rem = i % (768 * 768);
    int o = rem / 768, ii = rem % 768;
    b2t[i] = f2b(mu[(o * 768 + ii) * 3 + kk]);
  } else {                              // make_T (17 slots; slot 0 auto-zero)
    int i = (b - 33030) * 256 + tid;
    int c = i & 127, r = (i >> 7) & 127;
    int kk = (i >> 14) % 24, sl = (i >> 14) / 24;
    int t = (sl - 1) * 128 + r - c - 2;
    tt[i] = (t >= 0 && t < 2048) ? f2b(evec[t * 24 + kk]) : (u16)0;
  }
}

// ---------------------------------------------------------------------------
// Stage 128 rows x 64 u16 (16 KB) via async global_load_lds, XOR-swizzled:
// LDS slot (row, cb) holds global (row, cb ^ (row&7)).
__device__ __forceinline__ void stage128(const u16* __restrict__ g, int ld,
                                         u16* __restrict__ lds) {
  int tid = threadIdx.x;
  int r0 = tid >> 3, cb = tid & 7, wave = tid >> 6;
  #pragma unroll
  for (int s = 0; s < 4; ++s) {
    int row = r0 + (s << 5);
    int cbx = (cb ^ (row & 7)) << 3;
    gld16(g + row * ld + cbx, lds + (s << 11) + (wave << 9));
  }
}

// 128x128 tile MFMA over one K=64 slab (swizzle-aware reads).
__device__ __forceinline__ void mfma_tile(const u16* As, const u16* Bs, int lane,
                                          int wm, int wn, f32x4 acc[4][4]) {
  int cn = lane & 15, q = lane >> 4;
  #pragma unroll
  for (int ks = 0; ks < 2; ++ks) {
    int blk = ks * 4 + q;
    bf16x8 af[4], bg[4];
    #pragma unroll
    for (int i = 0; i < 4; ++i) {
      int row = wm + i * 16 + cn;
      af[i] = *(const bf16x8*)&As[row * 64 + ((blk ^ (row & 7)) << 3)];
    }
    #pragma unroll
    for (int j = 0; j < 4; ++j) {
      int row = wn + j * 16 + cn;
      bg[j] = *(const bf16x8*)&Bs[row * 64 + ((blk ^ (row & 7)) << 3)];
    }
    #pragma unroll
    for (int i = 0; i < 4; ++i)
      #pragma unroll
      for (int j = 0; j < 4; ++j)
        acc[i][j] = MFMA(af[i], bg[j], acc[i][j]);
  }
}

// 256x128 tile: wave owns 64 M-rows (wm = wave*64), all 128 N-cols. 32 MFMA/slab.
__device__ __forceinline__ void mfma_tile256(const u16* As, const u16* Bs, int lane,
                                             int wm, f32x4 acc[4][8]) {
  int cn = lane & 15, q = lane >> 4;
  #pragma unroll
  for (int ks = 0; ks < 2; ++ks) {
    int blk = ks * 4 + q;
    bf16x8 af[4], bg[8];
    #pragma unroll
    for (int i = 0; i < 4; ++i) {
      int row = wm + i * 16 + cn;
      af[i] = *(const bf16x8*)&As[row * 64 + ((blk ^ (row & 7)) << 3)];
    }
    #pragma unroll
    for (int j = 0; j < 8; ++j) {
      int row = j * 16 + cn;
      bg[j] = *(const bf16x8*)&Bs[row * 64 + ((blk ^ (row & 7)) << 3)];
    }
    #pragma unroll
    for (int i = 0; i < 4; ++i)
      #pragma unroll
      for (int j = 0; j < 8; ++j)
        acc[i][j] = MFMA(af[i], bg[j], acc[i][j]);
  }
}

// K2: Zt[18432 x 2048] = mphiT @ ub^T.  256x128 tiles, grid 72x16.
__global__ __launch_bounds__(256, 2) void k_gemm_zt(const u16* __restrict__ A,
                                                    const u16* __restrict__ B,
                                                    u16* __restrict__ C) {
  __shared__ __align__(16) u16 As[256 * 64];
  __shared__ __align__(16) u16 Bs[128 * 64];
  int bid = blockIdx.x;
  bid = (bid & 7) * 144 + (bid >> 3);   // XCD chunk swizzle (1152/8 = 144)
  int nt = bid & 15, mt = bid >> 4;
  int m0 = mt << 8, n0 = nt << 7;
  int tid = threadIdx.x, lane = tid & 63, wave = tid >> 6;
  int wm = wave << 6;
  f32x4 acc[4][8] = {};
  for (int kb = 0; kb < 12; ++kb) {
    stage128(A + m0 * 768 + kb * 64, 768, As);
    stage128(A + (m0 + 128) * 768 + kb * 64, 768, As + 8192);
    stage128(B + n0 * 768 + kb * 64, 768, Bs);
    __syncthreads();
    mfma_tile256(As, Bs, lane, wm, acc);
    __syncthreads();
  }
  int q = lane >> 4, cn = lane & 15;
  #pragma unroll
  for (int i = 0; i < 4; ++i)
    #pragma unroll
    for (int j = 0; j < 8; ++j)
      #pragma unroll
      for (int r = 0; r < 4; ++r) {
        int m = m0 + wm + i * 16 + q * 4 + r;
        int n = n0 + j * 16 + cn;
        C[m * 2048 + n] = f2b(acc[i][j][r]);
      }
}

// K3: delta = sum_k T_k @ Zt[k] + AR.  256x128 tiles; block = (db, a, s).
// Rows 0-127 of the A tile use dlt = 2a-s (slot dlt+1; slot 0 is all-zero),
// rows 128-255 use dlt = 2a+1-s.
__global__ __launch_bounds__(256, 2) void k_gemm_delta(const u16* __restrict__ tt,
                                                       const u16* __restrict__ zt,
                                                       const u16* __restrict__ ub,
                                                       const u16* __restrict__ b2t,
                                                       float* __restrict__ delta) {
  __shared__ __align__(16) u16 As[256 * 64];
  __shared__ __align__(16) u16 Bs[128 * 64];
  int bid = blockIdx.x;
  bid = (bid % 8) * 54 + bid / 8;       // XCD chunk swizzle (432/8 = 54)
  int db = bid % 6;
  int r2 = bid / 6;                 // [0,72) -> (a, s), s in [0, 2a+2)
  int a = 0, s = 0;
  for (;; ++a) { int cnt = 2 * a + 2; if (r2 < cnt) { s = r2; break; } r2 -= cnt; }
  int n0 = db << 7;
  int tid = threadIdx.x, lane = tid & 63, wave = tid >> 6;
  int wm = wave << 6;
  f32x4 acc[4][8] = {};
  int d1 = 2 * a + 1 - s;                         // slot for lower half = d1+1
  const u16* A0 = tt + (size_t)d1 * 24 * 16384;         // slot d1 (= dlt0+1)
  const u16* A1 = tt + (size_t)(d1 + 1) * 24 * 16384;   // slot d1+1
  for (int kk = 0; kk < 24; ++kk) {
    const u16* Bg = zt + kk * (768 * 2048) + n0 * 2048 + s * 128;
    #pragma unroll
    for (int hf = 0; hf < 2; ++hf) {
      stage128(A0 + kk * 16384 + hf * 64, 128, As);
      stage128(A1 + kk * 16384 + hf * 64, 128, As + 8192);
      stage128(Bg + hf * 64, 2048, Bs);
      __syncthreads();
      mfma_tile256(As, Bs, lane, wm, acc);
      __syncthreads();
    }
  }
  // AR taps: tap kku owned by s == min(kku, 2a+1)
  #pragma unroll
  for (int kku = 0; kku < 3; ++kku) {
    int owner = (kku <= 2 * a + 1) ? kku : 2 * a + 1;
    if (s != owner) continue;
    const u16* Au = ub + (2 + a * 256 - kku) * 768;
    const u16* Bg = b2t + kku * (768 * 768) + n0 * 768;
    for (int ic = 0; ic < 12; ++ic) {
      stage128(Au + ic * 64, 768, As);
      stage128(Au + 128 * 768 + ic * 64, 768, As + 8192);
      stage128(Bg + ic * 64, 768, Bs);
      __syncthreads();
      mfma_tile256(As, Bs, lane, wm, acc);
      __syncthreads();
    }
  }
  int q = lane >> 4, cn = lane & 15;
  #pragma unroll
  for (int i = 0; i < 4; ++i)
    #pragma unroll
    for (int j = 0; j < 8; ++j)
      #pragma unroll
      for (int r = 0; r < 4; ++r) {
        int m = a * 256 + wm + i * 16 + q * 4 + r;
        int n = n0 + j * 16 + cn;
        unsafeAtomicAdd(&delta[m * 768 + n], acc[i][j][r]);
      }
}

// ---------------------------------------------------------------------------
// chain init: R_0=[I|0], R_1=[A1|A2], Ct0=[R_1;R_0]^T, Ct1 right half=R_1^T, zero H.
__global__ void k_chain_init(const float* __restrict__ my, u16* __restrict__ Rbig,
                             u16* __restrict__ Ct0, u16* __restrict__ Ct1,
                             float* __restrict__ Hbuf) {
  int b = blockIdx.x, tid = threadIdx.x;
  if (b < 4608) {                       // R_0, R_1
    int i = b * 256 + tid;
    int o = i / 1536, q = i % 1536;
    Rbig[i] = (q == o) ? (u16)0x3F80 : (u16)0;
    Rbig[RJ + i] = f2b(my[i]);
  } else if (b < 13824) {               // Ct0[n][p]
    int i = (b - 4608) * 256 + tid;
    int n = i / 1536, p = i % 1536;
    u16 v;
    if (p < 768) v = f2b(my[p * 1536 + n]);
    else         v = (p - 768 == n) ? (u16)0x3F80 : (u16)0;
    Ct0[i] = v;
  } else if (b < 18432) {               // Ct1[n][768+i] = R_1[i][n]
    int i = (b - 13824) * 256 + tid;
    int n = i / 768, ii = i % 768;
    Ct1[n * 1536 + 768 + ii] = f2b(my[ii * 1536 + n]);
  } else {                              // zero Hbuf
    int i = (b - 18432) * 256 + tid;
    Hbuf[i] = 0.f;
  }
}

// M x 1536 x 1536 GEMM (B = Ct, [n][k] layout). Dual epilogue: row-major out +
// optional transposed write into the next doubling's Ct.
// mode 0: none; 1: tcol=m (R_2^T -> left); 2: m<768 -> 768+m (R_3^T right),
// m>=768 -> m-768 (R_4^T left).
__global__ __launch_bounds__(256) void k_gemm_R(const u16* __restrict__ A,
                                                const u16* __restrict__ Ct,
                                                u16* __restrict__ Co,
                                                u16* __restrict__ CtT, int mode) {
  __shared__ __align__(16) u16 As[128 * 64];
  __shared__ __align__(16) u16 Bs[128 * 64];
  int bid = blockIdx.x;
  int nt = bid % 12, mt = bid / 12;
  int m0 = mt << 7, n0 = nt << 7;
  int tid = threadIdx.x, lane = tid & 63, wave = tid >> 6;
  int wm = (wave & 1) << 6, wn = (wave >> 1) << 6;
  f32x4 acc[4][4] = {};
  for (int kb = 0; kb < 24; ++kb) {
    stage128(A + m0 * 1536 + kb * 64, 1536, As);
    stage128(Ct + n0 * 1536 + kb * 64, 1536, Bs);
    __syncthreads();
    mfma_tile(As, Bs, lane, wm, wn, acc);
    __syncthreads();
  }
  int q = lane >> 4, cn = lane & 15;
  #pragma unroll
  for (int i = 0; i < 4; ++i)
    #pragma unroll
    for (int j = 0; j < 4; ++j) {
      int n = n0 + wn + j * 16 + cn;
      int mb = m0 + wm + i * 16 + q * 4;
      u16 pk[4];
      #pragma unroll
      for (int r = 0; r < 4; ++r) {
        u16 v = f2b(acc[i][j][r]);
        Co[(mb + r) * 1536 + n] = v;
        pk[r] = v;
      }
      if (mode) {
        int tcol = (mode == 1) ? mb : ((mb < 768) ? 768 + mb : mb - 768);
        *(uint2*)&CtT[n * 1536 + tcol] = *(uint2*)pk;
      }
    }
}

// H[t][o] = sum_{i<=t&7} U_i[o][:] . delta[t-i][:]  (delta read f32, cast on the fly)
__global__ __launch_bounds__(256) void k_conv(const float* __restrict__ delta,
                                              const u16* __restrict__ Rbig,
                                              float* __restrict__ Hbuf) {
  __shared__ __align__(16) u16 As[128 * 64];
  __shared__ __align__(16) u16 Bs[128 * 64];
  int bid = blockIdx.x;
  bid = (bid & 7) * 48 + (bid >> 3);    // XCD chunk swizzle (384/8 = 48)
  int nt = bid % 6, mt = (bid / 6) % 16, sp = bid / 96;
  int m0 = mt << 7, n0 = nt << 7;
  int tid = threadIdx.x, lane = tid & 63, wave = tid >> 6;
  int wm = (wave & 1) << 6, wn = (wave >> 1) << 6;
  int trow = tid >> 3, cb = tid & 7;
  f32x4 acc[4][4] = {};
  for (int kb = 0; kb < 24; ++kb) {
    int i = 2 * sp + kb / 12, dinb = kb % 12;
    #pragma unroll
    for (int s = 0; s < 4; ++s) {
      int row = trow + (s << 5);
      int t = m0 + row;
      u16 pk[8] = {0, 0, 0, 0, 0, 0, 0, 0};
      if (i <= (t & 7)) {
        const float* src = delta + (t - i) * 768 + dinb * 64 + (cb << 3);
        f32x4 v0 = *(const f32x4*)src;
        f32x4 v1 = *(const f32x4*)(src + 4);
        #pragma unroll
        for (int e = 0; e < 4; ++e) { pk[e] = f2b(v0[e]); pk[4 + e] = f2b(v1[e]); }
      }
      *(u32x4*)&As[row * 64 + ((cb ^ (row & 7)) << 3)] = *(u32x4*)pk;
    }
    stage128(Rbig + i * RJ + n0 * 1536 + dinb * 64, 1536, Bs);
    __syncthreads();
    mfma_tile(As, Bs, lane, wm, wn, acc);
    __syncthreads();
  }
  int q = lane >> 4, cn = lane & 15;
  #pragma unroll
  for (int i = 0; i < 4; ++i)
    #pragma unroll
    for (int j = 0; j < 4; ++j)
      #pragma unroll
      for (int r = 0; r < 4; ++r) {
        int m = m0 + wm + i * 16 + q * 4 + r;
        int n = n0 + wn + j * 16 + cn;
        unsafeAtomicAdd(&Hbuf[m * 768 + n], acc[i][j][r]);
      }
}

// warm round A: S[c] = J @ S0[c] + h(8c-9), where S0[c][q] = H[8c-17-(q>=768)][o]
// (A-operand staged from Hbuf on the fly).  J rows: n<768 -> R_8[n], else R_7[n-768].
__global__ __launch_bounds__(256) void k_scan_roundA(const u16* __restrict__ Rbig,
                                                     const float* __restrict__ Hbuf,
                                                     u16* __restrict__ Sout) {
  __shared__ __align__(16) u16 As[128 * 64];
  __shared__ __align__(16) u16 Bs[128 * 64];
  int bid = blockIdx.x;
  int nt = bid % 12, mt = bid / 12;
  int m0 = mt << 7, n0 = nt << 7;
  const u16* Bg = (nt < 6) ? (Rbig + 8 * RJ + n0 * 1536)
                           : (Rbig + 7 * RJ + (n0 - 768) * 1536);
  int tid = threadIdx.x, lane = tid & 63, wave = tid >> 6;
  int wm = (wave & 1) << 6, wn = (wave >> 1) << 6;
  int trow = tid >> 3, cb = tid & 7;
  f32x4 acc[4][4] = {};
  for (int kb = 0; kb < 24; ++kb) {
    #pragma unroll
    for (int s = 0; s < 4; ++s) {
      int row = trow + (s << 5);
      int c = m0 + row;
      int qb = kb * 64 + (cb << 3);
      int side = (qb >= 768) ? 1 : 0;
      int o0 = qb - side * 768;
      int t = 8 * c - 17 - side;
      u16 pk[8] = {0, 0, 0, 0, 0, 0, 0, 0};
      if (t >= 0) {
        const float* src = Hbuf + t * 768 + o0;
        f32x4 v0 = *(const f32x4*)src;
        f32x4 v1 = *(const f32x4*)(src + 4);
        #pragma unroll
        for (int e = 0; e < 4; ++e) { pk[e] = f2b(v0[e]); pk[4 + e] = f2b(v1[e]); }
      }
      *(u32x4*)&As[row * 64 + ((cb ^ (row & 7)) << 3)] = *(u32x4*)pk;
    }
    stage128(Bg + kb * 64, 1536, Bs);
    __syncthreads();
    mfma_tile(As, Bs, lane, wm, wn, acc);
    __syncthreads();
  }
  int q = lane >> 4, cn = lane & 15;
  #pragma unroll
  for (int i = 0; i < 4; ++i)
    #pragma unroll
    for (int j = 0; j < 4; ++j)
      #pragma unroll
      for (int r = 0; r < 4; ++r) {
        int c = m0 + wm + i * 16 + q * 4 + r;
        int n = n0 + wn + j * 16 + cn;
        int side = (n < 768) ? 0 : 1;
        int t = 8 * c - 9 - side;
        int o = n - side * 768;
        float val = acc[i][j][r] + ((t >= 0) ? Hbuf[t * 768 + o] : 0.f);
        Sout[c * 1536 + n] = f2b(val);
      }
}

// warm round B: Snew[c] = J @ Sin[c] + h(8c-1)
__global__ __launch_bounds__(256) void k_scan_round(const u16* __restrict__ Sin,
                                                    const u16* __restrict__ Rbig,
                                                    const float* __restrict__ Hbuf,
                                                    u16* __restrict__ Sout) {
  __shared__ __align__(16) u16 As[128 * 64];
  __shared__ __align__(16) u16 Bs[128 * 64];
  int bid = blockIdx.x;
  int nt = bid % 12, mt = bid / 12;
  int m0 = mt << 7, n0 = nt << 7;
  const u16* Bg = (nt < 6) ? (Rbig + 8 * RJ + n0 * 1536)
                           : (Rbig + 7 * RJ + (n0 - 768) * 1536);
  int tid = threadIdx.x, lane = tid & 63, wave = tid >> 6;
  int wm = (wave & 1) << 6, wn = (wave >> 1) << 6;
  f32x4 acc[4][4] = {};
  for (int kb = 0; kb < 24; ++kb) {
    stage128(Sin + m0 * 1536 + kb * 64, 1536, As);
    stage128(Bg + kb * 64, 1536, Bs);
    __syncthreads();
    mfma_tile(As, Bs, lane, wm, wn, acc);
    __syncthreads();
  }
  int q = lane >> 4, cn = lane & 15;
  #pragma unroll
  for (int i = 0; i < 4; ++i)
    #pragma unroll
    for (int j = 0; j < 4; ++j)
      #pragma unroll
      for (int r = 0; r < 4; ++r) {
        int c = m0 + wm + i * 16 + q * 4 + r;
        int n = n0 + wn + j * 16 + cn;
        int side = (n < 768) ? 0 : 1;
        int t = 8 * c - 1 - side;
        int o = n - side * 768;
        float val = acc[i][j][r] + ((t >= 0) ? Hbuf[t * 768 + o] : 0.f);
        Sout[c * 1536 + n] = f2b(val);
      }
}

// output: y[8c+jj] = (R_{jj+1} @ S[c])[o] + H[8c+jj][o]
__global__ __launch_bounds__(256) void k_scan_out(const u16* __restrict__ Sin,
                                                  const u16* __restrict__ Rbig,
                                                  const float* __restrict__ Hbuf,
                                                  float* __restrict__ out) {
  __shared__ __align__(16) u16 As[128 * 64];
  __shared__ __align__(16) u16 Bs[128 * 64];
  int bid = blockIdx.x;
  int nt = bid % 48, mt = bid / 48;
  int m0 = mt << 7, n0 = nt << 7;
  const u16* Bg = Rbig + RJ + n0 * 1536;   // rows of [R_1; ...; R_8]
  int tid = threadIdx.x, lane = tid & 63, wave = tid >> 6;
  int wm = (wave & 1) << 6, wn = (wave >> 1) << 6;
  f32x4 acc[4][4] = {};
  for (int kb = 0; kb < 24; ++kb) {
    stage128(Sin + m0 * 1536 + kb * 64, 1536, As);
    stage128(Bg + kb * 64, 1536, Bs);
    __syncthreads();
    mfma_tile(As, Bs, lane, wm, wn, acc);
    __syncthreads();
  }
  int q = lane >> 4, cn = lane & 15;
  #pragma unroll
  for (int i = 0; i < 4; ++i)
    #pragma unroll
    for (int j = 0; j < 4; ++j)
      #pragma unroll
      for (int r = 0; r < 4; ++r) {
        int c = m0 + wm + i * 16 + q * 4 + r;
        int n = n0 + wn + j * 16 + cn;
        int jj = n / 768, o = n % 768;
        int t = 8 * c + jj;
        out[t * 768 + o] = acc[i][j][r] + Hbuf[t * 768 + o];
      }
}

// ---------------------------------------------------------------------------
extern "C" void kernel_launch(void* const* d_in, const int* in_sizes, int n_in,
                              void* d_out, int out_size, void* d_ws, size_t ws_size,
                              hipStream_t stream) {
  const float* u    = (const float*)d_in[0];
  const float* my   = (const float*)d_in[1];
  const float* mu   = (const float*)d_in[2];
  const float* mphi = (const float*)d_in[3];
  const float* ev   = (const float*)d_in[4];
  const float* evec = (const float*)d_in[5];
  float* out = (float*)d_out;
  char* ws = (char*)d_ws;

  u16*   ub    = (u16*)(ws + WS_UB);
  u16*   mphiT = (u16*)(ws + WS_MPHIT);
  u16*   b2t   = (u16*)(ws + WS_B2T);
  u16*   tt    = (u16*)(ws + WS_TT);
  u16*   zt    = (u16*)(ws + WS_ZT);
  float* delta = (float*)(ws + WS_DELTA);
  u16*   Rbig  = (u16*)(ws + OV_RBIG);
  u16*   Ct0   = (u16*)(ws + OV_CT0);
  u16*   Ct1   = (u16*)(ws + OV_CT1);
  u16*   Ct2   = (u16*)(ws + OV_CT2);
  float* Hbuf  = (float*)(ws + OV_HBUF);
  u16*   SA    = (u16*)(ws + OV_SBUF);
  u16*   SB    = SA + 256 * 1536;

  hipLaunchKernelGGL(k_prep, dim3(59142), dim3(256), 0, stream,
                     u, mphi, ev, mu, evec, delta, ub, mphiT, b2t, tt);
  hipLaunchKernelGGL(k_gemm_zt,    dim3(1152), dim3(256), 0, stream,
                     mphiT, ub + 2 * 768, zt);
  hipLaunchKernelGGL(k_gemm_delta, dim3(432),  dim3(256), 0, stream,
                     tt, zt, ub, b2t, delta);

  // --- scan prep (overlays zt; stream-ordered after k_gemm_delta) ---
  hipLaunchKernelGGL(k_chain_init, dim3(24576), dim3(256), 0, stream,
                     my, Rbig, Ct0, Ct1, Hbuf);
  hipLaunchKernelGGL(k_gemm_R, dim3(72),  dim3(256), 0, stream,
                     Rbig + RJ, Ct0, Rbig + 2 * RJ, Ct1, 1);            // R_2
  hipLaunchKernelGGL(k_gemm_R, dim3(144), dim3(256), 0, stream,
                     Rbig + RJ, Ct1, Rbig + 3 * RJ, Ct2, 2);            // R_3,R_4
  hipLaunchKernelGGL(k_gemm_R, dim3(288), dim3(256), 0, stream,
                     Rbig + RJ, Ct2, Rbig + 5 * RJ, (u16*)nullptr, 0);  // R_5..R_8

  hipLaunchKernelGGL(k_conv, dim3(384), dim3(256), 0, stream, delta, Rbig, Hbuf);

  // --- scan: 2 warm-up jumps (A of round 1 staged from Hbuf) + output ---
  hipLaunchKernelGGL(k_scan_roundA, dim3(24), dim3(256), 0, stream, Rbig, Hbuf, SA);
  hipLaunchKernelGGL(k_scan_round,  dim3(24), dim3(256), 0, stream, SA, Rbig, Hbuf, SB);
  hipLaunchKernelGGL(k_scan_out,    dim3(96), dim3(256), 0, stream, SB, Rbig, Hbuf, out);
}